// Round 1
// baseline (1308.828 us; speedup 1.0000x reference)
//
#include <hip/hip_runtime.h>
#include <hip/hip_bf16.h>
#include <math.h>

#define LRELU 0.01f

// ---------------- generic direct conv: thread = (b, co_group, out_pixel) ----
template<int CIN, int COUT, int CO_BLK, int K, int STRIDE, int PAD, bool RELU>
__global__ __launch_bounds__(256)
void conv_k(const float* __restrict__ in, const float* __restrict__ w,
            const float* __restrict__ bias, float* __restrict__ out,
            int B, int Hin, int Win, int Hout, int Wout) {
    const int HW = Hout * Wout;
    const int NG = COUT / CO_BLK;
    int gid = blockIdx.x * 256 + threadIdx.x;
    int total = B * NG * HW;
    if (gid >= total) return;
    int p   = gid % HW;
    int t   = gid / HW;
    int cog = t % NG;
    int b   = t / NG;
    int oh = p / Wout, ow = p % Wout;

    float acc[CO_BLK];
#pragma unroll
    for (int c = 0; c < CO_BLK; c++) acc[c] = bias[cog * CO_BLK + c];

    const float* inb = in + (b * CIN) * Hin * Win;
    for (int ci = 0; ci < CIN; ci++) {
#pragma unroll
        for (int kh = 0; kh < K; kh++) {
            int ih = oh * STRIDE + kh - PAD;
            if (PAD > 0 && (ih < 0 || ih >= Hin)) continue;
#pragma unroll
            for (int kw = 0; kw < K; kw++) {
                int iw = ow * STRIDE + kw - PAD;
                if (PAD > 0 && (iw < 0 || iw >= Win)) continue;
                float xv = inb[(ci * Hin + ih) * Win + iw];
#pragma unroll
                for (int c = 0; c < CO_BLK; c++) {
                    float wv = w[((cog * CO_BLK + c) * CIN + ci) * K * K + kh * K + kw];
                    acc[c] = fmaf(xv, wv, acc[c]);
                }
            }
        }
    }
    float* outb = out + (b * COUT + cog * CO_BLK) * HW + p;
#pragma unroll
    for (int c = 0; c < CO_BLK; c++) {
        float v = acc[c];
        if (RELU) v = (v >= 0.f) ? v : LRELU * v;
        outb[c * HW] = v;
    }
}

// ---------------- transpose conv (gather form), pad=0, w layout [CIN][COUT][K][K]
template<int CIN, int COUT, int CO_BLK, int K, int STRIDE, bool RELU, bool DO_TANH>
__global__ __launch_bounds__(256)
void convt_k(const float* __restrict__ in, const float* __restrict__ w,
             const float* __restrict__ bias, float* __restrict__ out,
             int B, int Hin, int Win, int Hout, int Wout) {
    const int HW = Hout * Wout;
    const int NG = COUT / CO_BLK;
    int gid = blockIdx.x * 256 + threadIdx.x;
    int total = B * NG * HW;
    if (gid >= total) return;
    int p   = gid % HW;
    int t   = gid / HW;
    int cog = t % NG;
    int b   = t / NG;
    int oh = p / Wout, ow = p % Wout;

    float acc[CO_BLK];
#pragma unroll
    for (int c = 0; c < CO_BLK; c++) acc[c] = bias[cog * CO_BLK + c];

    const float* inb = in + (b * CIN) * Hin * Win;
    for (int ci = 0; ci < CIN; ci++) {
#pragma unroll
        for (int kh = 0; kh < K; kh++) {
            int th = oh - kh;
            if (th < 0) continue;
            if (th % STRIDE) continue;
            int ih = th / STRIDE;
            if (ih >= Hin) continue;
#pragma unroll
            for (int kw = 0; kw < K; kw++) {
                int tw = ow - kw;
                if (tw < 0) continue;
                if (tw % STRIDE) continue;
                int iw = tw / STRIDE;
                if (iw >= Win) continue;
                float xv = inb[(ci * Hin + ih) * Win + iw];
#pragma unroll
                for (int c = 0; c < CO_BLK; c++) {
                    float wv = w[((ci * COUT + cog * CO_BLK + c) * K + kh) * K + kw];
                    acc[c] = fmaf(xv, wv, acc[c]);
                }
            }
        }
    }
    float* outb = out + (b * COUT + cog * CO_BLK) * HW + p;
#pragma unroll
    for (int c = 0; c < CO_BLK; c++) {
        float v = acc[c];
        if (RELU) v = (v >= 0.f) ? v : LRELU * v;
        if (DO_TANH) v = tanhf(v);
        outb[c * HW] = v;
    }
}

// ---------------- codebook squared norms ----------------
__global__ __launch_bounds__(256)
void cbnorm_k(const float* __restrict__ cb, float* __restrict__ cbn) {
    int k = blockIdx.x * 256 + threadIdx.x;
    if (k >= 512) return;
    const float* c = cb + k * 64;
    float s = 0.f;
#pragma unroll
    for (int d = 0; d < 64; d++) s = fmaf(c[d], c[d], s);
    cbn[k] = s;
}

// ---------------- vector quantizer: thread = one spatial position ----------
// lat: [B,64,HW] (NCHW). z out: [B,64,HW]. loss_acc: scalar (pre-zeroed).
__global__ __launch_bounds__(256)
void vq_k(const float* __restrict__ lat, const float* __restrict__ cb,
          const float* __restrict__ cbn, float* __restrict__ z,
          float* __restrict__ loss_acc, int B, int HW) {
    int gid = blockIdx.x * 256 + threadIdx.x;
    int N = B * HW;
    float myloss = 0.f;
    if (gid < N) {
        int p = gid % HW;
        int b = gid / HW;
        const float* lb = lat + (b * 64) * HW + p;
        float l[64];
#pragma unroll
        for (int d = 0; d < 64; d++) l[d] = lb[d * HW];

        float best = 1e30f;
        int bi = 0;
        for (int k = 0; k < 512; k++) {
            const float* c = cb + k * 64;
            float dot = 0.f;
#pragma unroll
            for (int d = 0; d < 64; d++) dot = fmaf(l[d], c[d], dot);
            float score = cbn[k] - 2.f * dot;
            if (score < best) { best = score; bi = k; }
        }
        const float* c = cb + bi * 64;
        float* zb = z + (b * 64) * HW + p;
#pragma unroll
        for (int d = 0; d < 64; d++) {
            float cv = c[d];
            float diff = cv - l[d];
            myloss = fmaf(diff, diff, myloss);
            zb[d * HW] = cv;
        }
    }
    __shared__ float red[256];
    red[threadIdx.x] = myloss;
    __syncthreads();
    for (int s = 128; s > 0; s >>= 1) {
        if ((int)threadIdx.x < s) red[threadIdx.x] += red[threadIdx.x + s];
        __syncthreads();
    }
    if (threadIdx.x == 0) atomicAdd(loss_acc, red[0]);
}

__global__ void loss_final_k(const float* __restrict__ loss_acc,
                             float* __restrict__ out_last, float inv_n) {
    if (blockIdx.x == 0 && threadIdx.x == 0)
        out_last[0] = 1.25f * loss_acc[0] * inv_n;
}

static inline int nblk(long long total) { return (int)((total + 255) / 256); }

extern "C" void kernel_launch(void* const* d_in, const int* in_sizes, int n_in,
                              void* d_out, int out_size, void* d_ws, size_t ws_size,
                              hipStream_t stream) {
    const float* x   = (const float*)d_in[0];
    const float* ew1 = (const float*)d_in[1];  const float* eb1 = (const float*)d_in[2];
    const float* ew2 = (const float*)d_in[3];  const float* eb2 = (const float*)d_in[4];
    const float* ew3 = (const float*)d_in[5];  const float* eb3 = (const float*)d_in[6];
    const float* ew4 = (const float*)d_in[7];  const float* eb4 = (const float*)d_in[8];
    const float* ew5 = (const float*)d_in[9];  const float* eb5 = (const float*)d_in[10];
    const float* dw1 = (const float*)d_in[11]; const float* db1 = (const float*)d_in[12];
    const float* dw2 = (const float*)d_in[13]; const float* db2 = (const float*)d_in[14];
    const float* dw3 = (const float*)d_in[15]; const float* db3 = (const float*)d_in[16];
    const float* dw4 = (const float*)d_in[17]; const float* db4 = (const float*)d_in[18];
    const float* cb  = (const float*)d_in[19];
    float* out = (float*)d_out;

    const int B = in_sizes[0] / (256 * 256);   // 64

    // workspace layout (bytes): A ping (36MB) | B pong (17MB) | cbn | loss
    char* ws = (char*)d_ws;
    float* Abuf = (float*)(ws + 0);
    float* Bbuf = (float*)(ws + (36u << 20));
    float* cbn  = (float*)(ws + (53u << 20));
    float* loss = (float*)(ws + (53u << 20) + 4096);

    hipMemsetAsync(loss, 0, sizeof(float), stream);
    cbnorm_k<<<2, 256, 0, stream>>>(cb, cbn);

    // ---- encoder ----
    // e1: [B,1,256,256] -> A [B,8,127,127]
    conv_k<1, 8, 8, 4, 2, 0, true><<<nblk((long long)B * 1 * 127 * 127), 256, 0, stream>>>(
        x, ew1, eb1, Abuf, B, 256, 256, 127, 127);
    // e2: A -> B [B,16,62,62]
    conv_k<8, 16, 16, 4, 2, 0, true><<<nblk((long long)B * 1 * 62 * 62), 256, 0, stream>>>(
        Abuf, ew2, eb2, Bbuf, B, 127, 127, 62, 62);
    // e3: B -> A [B,32,30,30]
    conv_k<16, 32, 16, 4, 2, 0, true><<<nblk((long long)B * 2 * 30 * 30), 256, 0, stream>>>(
        Bbuf, ew3, eb3, Abuf, B, 62, 62, 30, 30);
    // e4: A -> B [B,32,30,30]  (3x3 pad1)
    conv_k<32, 32, 16, 3, 1, 1, true><<<nblk((long long)B * 2 * 30 * 30), 256, 0, stream>>>(
        Abuf, ew4, eb4, Bbuf, B, 30, 30, 30, 30);
    // e5: B -> A [B,64,30,30]  (1x1)
    conv_k<32, 64, 16, 1, 1, 0, true><<<nblk((long long)B * 4 * 30 * 30), 256, 0, stream>>>(
        Bbuf, ew5, eb5, Abuf, B, 30, 30, 30, 30);

    // ---- VQ: lat=A -> z=B, loss accumulated ----
    vq_k<<<nblk((long long)B * 900), 256, 0, stream>>>(Abuf, cb, cbn, Bbuf, loss, B, 900);

    // ---- decoder ----
    // d1: B(z) -> A [B,32,30,30] (3x3 pad1)
    conv_k<64, 32, 16, 3, 1, 1, true><<<nblk((long long)B * 2 * 30 * 30), 256, 0, stream>>>(
        Bbuf, dw1, db1, Abuf, B, 30, 30, 30, 30);
    // d2: A -> B [B,16,63,63]  (convT 4x4 s2 op1)
    convt_k<32, 16, 16, 4, 2, true, false><<<nblk((long long)B * 1 * 63 * 63), 256, 0, stream>>>(
        Abuf, dw2, db2, Bbuf, B, 30, 30, 63, 63);
    // d3: B -> A [B,8,129,129] (convT 4x4 s2 op1)
    convt_k<16, 8, 8, 4, 2, true, false><<<nblk((long long)B * 1 * 129 * 129), 256, 0, stream>>>(
        Bbuf, dw3, db3, Abuf, B, 63, 63, 129, 129);
    // d4: A -> out [B,1,260,260] (convT 4x4 s2 op0, tanh)
    convt_k<8, 1, 1, 4, 2, false, true><<<nblk((long long)B * 1 * 260 * 260), 256, 0, stream>>>(
        Abuf, dw4, db4, out, B, 129, 129, 260, 260);

    // ---- scalar loss -> last output element ----
    loss_final_k<<<1, 64, 0, stream>>>(loss, out + (out_size - 1),
                                       1.0f / ((float)B * 900.f * 64.f));
}

// Round 2
// 999.107 us; speedup vs baseline: 1.3100x; 1.3100x over previous
//
#include <hip/hip_runtime.h>
#include <hip/hip_bf16.h>
#include <math.h>

#define LRELU 0.01f

// ---------------- forward conv core (templated bounds-check) ----------------
template<int CIN, int CO_BLK, int K, int STRIDE, int PAD, bool CHECK>
__device__ __forceinline__ void conv_acc(const float* __restrict__ inb,
                                         const float* __restrict__ wb,
                                         int oh, int ow, int Hin, int Win,
                                         float* acc) {
    for (int ci = 0; ci < CIN; ci++) {
#pragma unroll
        for (int kh = 0; kh < K; kh++) {
            int ih = oh * STRIDE + kh - PAD;
            if (CHECK && (ih < 0 || ih >= Hin)) continue;
#pragma unroll
            for (int kw = 0; kw < K; kw++) {
                int iw = ow * STRIDE + kw - PAD;
                if (CHECK && (iw < 0 || iw >= Win)) continue;
                float x = inb[(ci * Hin + ih) * Win + iw];
#pragma unroll
                for (int c = 0; c < CO_BLK; c++)
                    acc[c] = fmaf(x, wb[(c * CIN + ci) * K * K + kh * K + kw], acc[c]);
            }
        }
    }
}

// grid: (ceil(HW/256), COUT/CO_BLK, B)  — cog & b are block-uniform
template<int CIN, int COUT, int CO_BLK, int K, int STRIDE, int PAD, bool RELU>
__global__ __launch_bounds__(256)
void conv_k(const float* __restrict__ in, const float* __restrict__ w,
            const float* __restrict__ bias, float* __restrict__ out,
            int Hin, int Win, int Hout, int Wout) {
    const int HW = Hout * Wout;
    int p = blockIdx.x * 256 + threadIdx.x;
    if (p >= HW) return;
    int cog = blockIdx.y, b = blockIdx.z;
    int oh = p / Wout, ow = p - oh * Wout;

    float acc[CO_BLK];
#pragma unroll
    for (int c = 0; c < CO_BLK; c++) acc[c] = bias[cog * CO_BLK + c];

    const float* inb = in + (b * CIN) * Hin * Win;
    const float* wb  = w + (cog * CO_BLK) * CIN * K * K;

    bool interior = (PAD == 0) ||
        (oh * STRIDE >= PAD && oh * STRIDE + K - PAD <= Hin &&
         ow * STRIDE >= PAD && ow * STRIDE + K - PAD <= Win);
    if (interior)
        conv_acc<CIN, CO_BLK, K, STRIDE, PAD, false>(inb, wb, oh, ow, Hin, Win, acc);
    else
        conv_acc<CIN, CO_BLK, K, STRIDE, PAD, true >(inb, wb, oh, ow, Hin, Win, acc);

    float* outb = out + (b * COUT + cog * CO_BLK) * HW + p;
#pragma unroll
    for (int c = 0; c < CO_BLK; c++) {
        float v = acc[c];
        if (RELU) v = (v >= 0.f) ? v : LRELU * v;
        outb[c * HW] = v;
    }
}

// ---------------- transpose conv K=4 S=2, parity-class grid --------------
// grid: (4*nb2, COUT/CO_BLK, B). class = blockIdx.x/nb2 -> (py,px) parity.
// For parity class, taps are kh=py+2a, kw=px+2q -> ih=oh2-a, iw=ow2-q.
template<int CIN, int COUT, int CO_BLK, bool RELU, bool DO_TANH>
__global__ __launch_bounds__(256)
void convt_k(const float* __restrict__ in, const float* __restrict__ w,
             const float* __restrict__ bias, float* __restrict__ out,
             int Hin, int Win, int Hout, int Wout, int nb2) {
    const int HW = Hout * Wout;
    int cls = blockIdx.x / nb2;
    int blk = blockIdx.x - cls * nb2;
    int py = cls & 1, px = cls >> 1;
    int H2 = (Hout - py + 1) >> 1;
    int W2 = (Wout - px + 1) >> 1;
    int idx = blk * 256 + threadIdx.x;
    if (idx >= H2 * W2) return;
    int oh2 = idx / W2, ow2 = idx - oh2 * W2;
    int oh = oh2 * 2 + py, ow = ow2 * 2 + px;
    int cog = blockIdx.y, b = blockIdx.z;

    float acc[CO_BLK];
#pragma unroll
    for (int c = 0; c < CO_BLK; c++) acc[c] = bias[cog * CO_BLK + c];

    const float* inb = in + (b * CIN) * Hin * Win;

#pragma unroll
    for (int a = 0; a < 2; a++) {
        int ih = oh2 - a;
        bool vy = (ih >= 0) && (ih < Hin);
#pragma unroll
        for (int q = 0; q < 2; q++) {
            int iw = ow2 - q;
            bool v = vy && (iw >= 0) && (iw < Win);
            int kh = py + 2 * a, kw = px + 2 * q;
            for (int ci = 0; ci < CIN; ci++) {
                float x = v ? inb[(ci * Hin + ih) * Win + iw] : 0.f;
#pragma unroll
                for (int c = 0; c < CO_BLK; c++)
                    acc[c] = fmaf(x, w[((ci * COUT + cog * CO_BLK + c) * 4 + kh) * 4 + kw],
                                  acc[c]);
            }
        }
    }
    float* outb = out + (b * COUT + cog * CO_BLK) * HW + oh * Wout + ow;
#pragma unroll
    for (int c = 0; c < CO_BLK; c++) {
        float v = acc[c];
        if (RELU) v = (v >= 0.f) ? v : LRELU * v;
        if (DO_TANH) v = tanhf(v);
        outb[c * HW] = v;
    }
}

// ---------------- codebook squared norms ----------------
__global__ __launch_bounds__(256)
void cbnorm_k(const float* __restrict__ cb, float* __restrict__ cbn) {
    int k = blockIdx.x * 256 + threadIdx.x;
    if (k >= 512) return;
    const float* c = cb + k * 64;
    float s = 0.f;
#pragma unroll
    for (int d = 0; d < 64; d++) s = fmaf(c[d], c[d], s);
    cbn[k] = s;
}

// ---------------- vector quantizer ----------------
// 8 lanes per position: 32 positions/block (tid&31), dim-half dh=(tid>>5)&1,
// code-quarter cq=tid>>6 (128 codes each). Dim halves combined via shfl_xor 32
// (in-wave), code quarters via LDS with lowest-index tie-break.
__global__ __launch_bounds__(256)
void vq_k(const float* __restrict__ lat, const float* __restrict__ cb,
          const float* __restrict__ cbn, float* __restrict__ z,
          float* __restrict__ loss_acc, int B, int HW) {
    const int tid  = threadIdx.x;
    const int posl = tid & 31;
    const int dh   = (tid >> 5) & 1;
    const int cq   = tid >> 6;
    const int pos  = blockIdx.x * 32 + posl;
    const int N    = B * HW;

    __shared__ float sb[4][33];
    __shared__ int   si[4][33];
    __shared__ int   sbi[32];
    __shared__ float red[256];

    float best = 3.4e38f; int bi = 0;
    int b = 0, p = 0;
    if (pos < N) {
        b = pos / HW; p = pos - b * HW;
        const float* lb = lat + (b * 64 + dh * 32) * HW + p;
        float l[32];
#pragma unroll
        for (int i = 0; i < 32; i++) l[i] = lb[i * HW];

#pragma unroll 2
        for (int k0 = 0; k0 < 128; k0++) {
            int k = cq * 128 + k0;
            const float4* cr = (const float4*)(cb + (k * 64 + dh * 32));
            float dot = 0.f;
#pragma unroll
            for (int i = 0; i < 8; i++) {
                float4 v4 = cr[i];
                dot = fmaf(l[4 * i + 0], v4.x, dot);
                dot = fmaf(l[4 * i + 1], v4.y, dot);
                dot = fmaf(l[4 * i + 2], v4.z, dot);
                dot = fmaf(l[4 * i + 3], v4.w, dot);
            }
            float full = dot + __shfl_xor(dot, 32);  // both dim-halves -> identical
            float score = cbn[k] - 2.f * full;
            if (score < best) { best = score; bi = k; }
        }
    }
    if (dh == 0) { sb[cq][posl] = best; si[cq][posl] = bi; }
    __syncthreads();
    if (tid < 32) {
        float bb = sb[0][tid]; int ib = si[0][tid];
#pragma unroll
        for (int q = 1; q < 4; q++) {           // ascending q = ascending k:
            float s2 = sb[q][tid];              // strict < keeps lowest index
            if (s2 < bb) { bb = s2; ib = si[q][tid]; }
        }
        sbi[tid] = ib;
    }
    __syncthreads();

    float myloss = 0.f;
    if (pos < N) {
        int bif = sbi[posl];
        int dbase = (tid >> 5) * 8;             // 8 threads x 8 dims = 64
        const float* crow = cb + bif * 64;
        const float* lrow = lat + b * 64 * HW + p;
        float*       zrow = z   + b * 64 * HW + p;
#pragma unroll
        for (int j = 0; j < 8; j++) {
            int d = dbase + j;
            float cv = crow[d];
            float lv = lrow[d * HW];
            zrow[d * HW] = cv;
            float df = cv - lv;
            myloss = fmaf(df, df, myloss);
        }
    }
    red[tid] = myloss;
    __syncthreads();
    for (int s = 128; s > 0; s >>= 1) {
        if (tid < s) red[tid] += red[tid + s];
        __syncthreads();
    }
    if (tid == 0) atomicAdd(loss_acc, red[0]);
}

__global__ void loss_final_k(const float* __restrict__ loss_acc,
                             float* __restrict__ out_last, float inv_n) {
    if (blockIdx.x == 0 && threadIdx.x == 0)
        out_last[0] = 1.25f * loss_acc[0] * inv_n;
}

static inline int nblk(long long total) { return (int)((total + 255) / 256); }

extern "C" void kernel_launch(void* const* d_in, const int* in_sizes, int n_in,
                              void* d_out, int out_size, void* d_ws, size_t ws_size,
                              hipStream_t stream) {
    const float* x   = (const float*)d_in[0];
    const float* ew1 = (const float*)d_in[1];  const float* eb1 = (const float*)d_in[2];
    const float* ew2 = (const float*)d_in[3];  const float* eb2 = (const float*)d_in[4];
    const float* ew3 = (const float*)d_in[5];  const float* eb3 = (const float*)d_in[6];
    const float* ew4 = (const float*)d_in[7];  const float* eb4 = (const float*)d_in[8];
    const float* ew5 = (const float*)d_in[9];  const float* eb5 = (const float*)d_in[10];
    const float* dw1 = (const float*)d_in[11]; const float* db1 = (const float*)d_in[12];
    const float* dw2 = (const float*)d_in[13]; const float* db2 = (const float*)d_in[14];
    const float* dw3 = (const float*)d_in[15]; const float* db3 = (const float*)d_in[16];
    const float* dw4 = (const float*)d_in[17]; const float* db4 = (const float*)d_in[18];
    const float* cb  = (const float*)d_in[19];
    float* out = (float*)d_out;

    const int B = in_sizes[0] / (256 * 256);   // 64

    char* ws = (char*)d_ws;
    float* Abuf = (float*)(ws + 0);
    float* Bbuf = (float*)(ws + (36u << 20));
    float* cbn  = (float*)(ws + (53u << 20));
    float* loss = (float*)(ws + (53u << 20) + 4096);

    hipMemsetAsync(loss, 0, sizeof(float), stream);
    cbnorm_k<<<2, 256, 0, stream>>>(cb, cbn);

    // ---- encoder ----
    conv_k<1, 8, 8, 4, 2, 0, true><<<dim3(nblk(127 * 127), 1, B), 256, 0, stream>>>(
        x, ew1, eb1, Abuf, 256, 256, 127, 127);
    conv_k<8, 16, 8, 4, 2, 0, true><<<dim3(nblk(62 * 62), 2, B), 256, 0, stream>>>(
        Abuf, ew2, eb2, Bbuf, 127, 127, 62, 62);
    conv_k<16, 32, 4, 4, 2, 0, true><<<dim3(nblk(900), 8, B), 256, 0, stream>>>(
        Bbuf, ew3, eb3, Abuf, 62, 62, 30, 30);
    conv_k<32, 32, 4, 3, 1, 1, true><<<dim3(nblk(900), 8, B), 256, 0, stream>>>(
        Abuf, ew4, eb4, Bbuf, 30, 30, 30, 30);
    conv_k<32, 64, 4, 1, 1, 0, true><<<dim3(nblk(900), 16, B), 256, 0, stream>>>(
        Bbuf, ew5, eb5, Abuf, 30, 30, 30, 30);

    // ---- VQ: lat=A -> z=B ----
    vq_k<<<(B * 900 + 31) / 32, 256, 0, stream>>>(Abuf, cb, cbn, Bbuf, loss, B, 900);

    // ---- decoder ----
    conv_k<64, 32, 4, 3, 1, 1, true><<<dim3(nblk(900), 8, B), 256, 0, stream>>>(
        Bbuf, dw1, db1, Abuf, 30, 30, 30, 30);
    {   // d2: [B,32,30,30] -> [B,16,63,63]
        int nb2 = (32 * 32 + 255) / 256;   // 4
        convt_k<32, 16, 8, true, false><<<dim3(4 * nb2, 2, B), 256, 0, stream>>>(
            Abuf, dw2, db2, Bbuf, 30, 30, 63, 63, nb2);
    }
    {   // d3: [B,16,63,63] -> [B,8,129,129]
        int nb2 = (65 * 65 + 255) / 256;   // 17
        convt_k<16, 8, 8, true, false><<<dim3(4 * nb2, 1, B), 256, 0, stream>>>(
            Bbuf, dw3, db3, Abuf, 63, 63, 129, 129, nb2);
    }
    {   // d4: [B,8,129,129] -> [B,1,260,260] + tanh
        int nb2 = (130 * 130 + 255) / 256; // 67
        convt_k<8, 1, 1, false, true><<<dim3(4 * nb2, 1, B), 256, 0, stream>>>(
            Abuf, dw4, db4, out, 129, 129, 260, 260, nb2);
    }

    loss_final_k<<<1, 64, 0, stream>>>(loss, out + (out_size - 1),
                                       1.0f / ((float)B * 900.f * 64.f));
}

// Round 3
// 854.864 us; speedup vs baseline: 1.5310x; 1.1687x over previous
//
#include <hip/hip_runtime.h>
#include <hip/hip_bf16.h>
#include <math.h>

#define LRELU 0.01f

// ---------------- forward conv core (templated bounds-check) ----------------
template<int CIN, int CO_BLK, int K, int STRIDE, int PAD, bool CHECK>
__device__ __forceinline__ void conv_acc(const float* __restrict__ inb,
                                         const float* __restrict__ wb,
                                         int oh, int ow, int Hin, int Win,
                                         float* acc) {
    for (int ci = 0; ci < CIN; ci++) {
#pragma unroll
        for (int kh = 0; kh < K; kh++) {
            int ih = oh * STRIDE + kh - PAD;
            if (CHECK && (ih < 0 || ih >= Hin)) continue;
#pragma unroll
            for (int kw = 0; kw < K; kw++) {
                int iw = ow * STRIDE + kw - PAD;
                if (CHECK && (iw < 0 || iw >= Win)) continue;
                float x = inb[(ci * Hin + ih) * Win + iw];
#pragma unroll
                for (int c = 0; c < CO_BLK; c++)
                    acc[c] = fmaf(x, wb[(c * CIN + ci) * K * K + kh * K + kw], acc[c]);
            }
        }
    }
}

// grid: (ceil(HW/256), COUT/CO_BLK, B)  — cog & b are block-uniform
template<int CIN, int COUT, int CO_BLK, int K, int STRIDE, int PAD, bool RELU>
__global__ __launch_bounds__(256)
void conv_k(const float* __restrict__ in, const float* __restrict__ w,
            const float* __restrict__ bias, float* __restrict__ out,
            int Hin, int Win, int Hout, int Wout) {
    const int HW = Hout * Wout;
    int p = blockIdx.x * 256 + threadIdx.x;
    if (p >= HW) return;
    int cog = blockIdx.y, b = blockIdx.z;
    int oh = p / Wout, ow = p - oh * Wout;

    float acc[CO_BLK];
#pragma unroll
    for (int c = 0; c < CO_BLK; c++) acc[c] = bias[cog * CO_BLK + c];

    const float* inb = in + (b * CIN) * Hin * Win;
    const float* wb  = w + (cog * CO_BLK) * CIN * K * K;

    bool interior = (PAD == 0) ||
        (oh * STRIDE >= PAD && oh * STRIDE + K - PAD <= Hin &&
         ow * STRIDE >= PAD && ow * STRIDE + K - PAD <= Win);
    if (interior)
        conv_acc<CIN, CO_BLK, K, STRIDE, PAD, false>(inb, wb, oh, ow, Hin, Win, acc);
    else
        conv_acc<CIN, CO_BLK, K, STRIDE, PAD, true >(inb, wb, oh, ow, Hin, Win, acc);

    float* outb = out + (b * COUT + cog * CO_BLK) * HW + p;
#pragma unroll
    for (int c = 0; c < CO_BLK; c++) {
        float v = acc[c];
        if (RELU) v = (v >= 0.f) ? v : LRELU * v;
        outb[c * HW] = v;
    }
}

// ---------------- transpose conv K=4 S=2, parity-class grid --------------
template<int CIN, int COUT, int CO_BLK, bool RELU, bool DO_TANH>
__global__ __launch_bounds__(256)
void convt_k(const float* __restrict__ in, const float* __restrict__ w,
             const float* __restrict__ bias, float* __restrict__ out,
             int Hin, int Win, int Hout, int Wout, int nb2) {
    const int HW = Hout * Wout;
    int cls = blockIdx.x / nb2;
    int blk = blockIdx.x - cls * nb2;
    int py = cls & 1, px = cls >> 1;
    int H2 = (Hout - py + 1) >> 1;
    int W2 = (Wout - px + 1) >> 1;
    int idx = blk * 256 + threadIdx.x;
    if (idx >= H2 * W2) return;
    int oh2 = idx / W2, ow2 = idx - oh2 * W2;
    int oh = oh2 * 2 + py, ow = ow2 * 2 + px;
    int cog = blockIdx.y, b = blockIdx.z;

    float acc[CO_BLK];
#pragma unroll
    for (int c = 0; c < CO_BLK; c++) acc[c] = bias[cog * CO_BLK + c];

    const float* inb = in + (b * CIN) * Hin * Win;

#pragma unroll
    for (int a = 0; a < 2; a++) {
        int ih = oh2 - a;
        bool vy = (ih >= 0) && (ih < Hin);
#pragma unroll
        for (int q = 0; q < 2; q++) {
            int iw = ow2 - q;
            bool v = vy && (iw >= 0) && (iw < Win);
            int kh = py + 2 * a, kw = px + 2 * q;
            for (int ci = 0; ci < CIN; ci++) {
                float x = v ? inb[(ci * Hin + ih) * Win + iw] : 0.f;
#pragma unroll
                for (int c = 0; c < CO_BLK; c++)
                    acc[c] = fmaf(x, w[((ci * COUT + cog * CO_BLK + c) * 4 + kh) * 4 + kw],
                                  acc[c]);
            }
        }
    }
    float* outb = out + (b * COUT + cog * CO_BLK) * HW + oh * Wout + ow;
#pragma unroll
    for (int c = 0; c < CO_BLK; c++) {
        float v = acc[c];
        if (RELU) v = (v >= 0.f) ? v : LRELU * v;
        if (DO_TANH) v = tanhf(v);
        outb[c * HW] = v;
    }
}

// ---------------- codebook HALF squared norms (0.5*||c||^2) ----------------
__global__ __launch_bounds__(256)
void cbnorm_k(const float* __restrict__ cb, float* __restrict__ hcbn) {
    int k = blockIdx.x * 256 + threadIdx.x;
    if (k >= 512) return;
    const float* c = cb + k * 64;
    float s = 0.f;
#pragma unroll
    for (int d = 0; d < 64; d++) s = fmaf(c[d], c[d], s);
    hcbn[k] = 0.5f * s;
}

// ---------------- VQ stage 1: blocked argmin -------------------------------
// grid: (ceil(N/256), 4). Block = 256 consecutive positions vs one
// 128-code quarter. Lane quad (dq=tid&3) splits the 64 dims 4-ways;
// each lane holds 4 positions (pg, pg+64, pg+128, pg+192) x 16 dims.
// Codebook staged in LDS in 64-code (16KB) chunks; argmin across the
// 4 grid.y quarters merged via atomicMin on packed (score|idx) keys.
__global__ __launch_bounds__(256)
void vq_argmin_k(const float* __restrict__ lat, const float* __restrict__ cb,
                 const float* __restrict__ hcbn,
                 unsigned long long* __restrict__ keys, int B, int HW) {
    __shared__ float4 scb4[1024];   // 64 codes x 64 dims = 16KB
    __shared__ float  shn[64];
    const int tid = threadIdx.x;
    const int dq  = tid & 3;        // dim quarter
    const int pg  = tid >> 2;       // position group 0..63
    const int q   = blockIdx.y;     // code quarter (128 codes)
    const int N   = B * HW;
    const int posbase = blockIdx.x * 256;

    float l[4][16];
    int   pidx[4];
    bool  valid[4];
#pragma unroll
    for (int j = 0; j < 4; j++) {
        int pos = posbase + pg + 64 * j;
        pidx[j] = pos;
        valid[j] = pos < N;
        if (valid[j]) {
            int b = pos / HW, p = pos - b * HW;
            const float* lb = lat + ((size_t)b * 64 + dq * 16) * HW + p;
#pragma unroll
            for (int i = 0; i < 16; i++) l[j][i] = lb[i * HW];
        } else {
#pragma unroll
            for (int i = 0; i < 16; i++) l[j][i] = 0.f;
        }
    }

    float best[4] = {3.4e38f, 3.4e38f, 3.4e38f, 3.4e38f};
    int   bi[4]   = {0, 0, 0, 0};

    for (int c = 0; c < 2; c++) {
        const int kbase = q * 128 + c * 64;
        const float4* src = (const float4*)(cb + (size_t)kbase * 64);
        __syncthreads();
#pragma unroll
        for (int i = 0; i < 4; i++) scb4[tid + 256 * i] = src[tid + 256 * i];
        if (tid < 64) shn[tid] = hcbn[kbase + tid];
        __syncthreads();

#pragma unroll 2
        for (int k0 = 0; k0 < 64; k0++) {
            float4 c0 = scb4[k0 * 16 + dq * 4 + 0];
            float4 c1 = scb4[k0 * 16 + dq * 4 + 1];
            float4 c2 = scb4[k0 * 16 + dq * 4 + 2];
            float4 c3 = scb4[k0 * 16 + dq * 4 + 3];
            float hn = shn[k0];
#pragma unroll
            for (int j = 0; j < 4; j++) {
                float dot = 0.f;
                dot = fmaf(l[j][0],  c0.x, dot); dot = fmaf(l[j][1],  c0.y, dot);
                dot = fmaf(l[j][2],  c0.z, dot); dot = fmaf(l[j][3],  c0.w, dot);
                dot = fmaf(l[j][4],  c1.x, dot); dot = fmaf(l[j][5],  c1.y, dot);
                dot = fmaf(l[j][6],  c1.z, dot); dot = fmaf(l[j][7],  c1.w, dot);
                dot = fmaf(l[j][8],  c2.x, dot); dot = fmaf(l[j][9],  c2.y, dot);
                dot = fmaf(l[j][10], c2.z, dot); dot = fmaf(l[j][11], c2.w, dot);
                dot = fmaf(l[j][12], c3.x, dot); dot = fmaf(l[j][13], c3.y, dot);
                dot = fmaf(l[j][14], c3.z, dot); dot = fmaf(l[j][15], c3.w, dot);
                float full = dot + __shfl_xor(dot, 1);
                full += __shfl_xor(full, 2);
                float score = hn - full;        // 0.5*||c||^2 - <l,c>
                if (score < best[j]) { best[j] = score; bi[j] = kbase + k0; }
            }
        }
    }

    if (dq == 0) {
#pragma unroll
        for (int j = 0; j < 4; j++) {
            if (!valid[j]) continue;
            unsigned u = __float_as_uint(best[j]);
            u = ((int)u < 0) ? ~u : (u | 0x80000000u);   // orderable
            unsigned long long key = ((unsigned long long)u << 32) | (unsigned)bi[j];
            atomicMin(&keys[pidx[j]], key);
        }
    }
}

// ---------------- VQ stage 2: gather winner, write z, loss -----------------
__global__ __launch_bounds__(256)
void vq_finalize_k(const float* __restrict__ lat, const float* __restrict__ cb,
                   const unsigned long long* __restrict__ keys,
                   float* __restrict__ z, float* __restrict__ loss_acc,
                   int B, int HW) {
    int gid = blockIdx.x * 256 + threadIdx.x;
    const int N = B * HW;
    float myloss = 0.f;
    if (gid < N) {
        int b = gid / HW, p = gid - b * HW;
        int idx = (int)(unsigned)(keys[gid] & 0xFFFFFFFFull);
        const float4* crow = (const float4*)(cb + (size_t)idx * 64);
        const float* lrow = lat + (size_t)b * 64 * HW + p;
        float*       zrow = z   + (size_t)b * 64 * HW + p;
#pragma unroll
        for (int i = 0; i < 16; i++) {
            float4 cv = crow[i];
            float lv0 = lrow[(4 * i + 0) * HW];
            float lv1 = lrow[(4 * i + 1) * HW];
            float lv2 = lrow[(4 * i + 2) * HW];
            float lv3 = lrow[(4 * i + 3) * HW];
            zrow[(4 * i + 0) * HW] = cv.x;
            zrow[(4 * i + 1) * HW] = cv.y;
            zrow[(4 * i + 2) * HW] = cv.z;
            zrow[(4 * i + 3) * HW] = cv.w;
            float d0 = cv.x - lv0, d1 = cv.y - lv1, d2 = cv.z - lv2, d3 = cv.w - lv3;
            myloss = fmaf(d0, d0, myloss);
            myloss = fmaf(d1, d1, myloss);
            myloss = fmaf(d2, d2, myloss);
            myloss = fmaf(d3, d3, myloss);
        }
    }
    __shared__ float red[256];
    red[threadIdx.x] = myloss;
    __syncthreads();
    for (int s = 128; s > 0; s >>= 1) {
        if ((int)threadIdx.x < s) red[threadIdx.x] += red[threadIdx.x + s];
        __syncthreads();
    }
    if (threadIdx.x == 0) atomicAdd(loss_acc, red[0]);
}

__global__ void loss_final_k(const float* __restrict__ loss_acc,
                             float* __restrict__ out_last, float inv_n) {
    if (blockIdx.x == 0 && threadIdx.x == 0)
        out_last[0] = 1.25f * loss_acc[0] * inv_n;
}

static inline int nblk(long long total) { return (int)((total + 255) / 256); }

extern "C" void kernel_launch(void* const* d_in, const int* in_sizes, int n_in,
                              void* d_out, int out_size, void* d_ws, size_t ws_size,
                              hipStream_t stream) {
    const float* x   = (const float*)d_in[0];
    const float* ew1 = (const float*)d_in[1];  const float* eb1 = (const float*)d_in[2];
    const float* ew2 = (const float*)d_in[3];  const float* eb2 = (const float*)d_in[4];
    const float* ew3 = (const float*)d_in[5];  const float* eb3 = (const float*)d_in[6];
    const float* ew4 = (const float*)d_in[7];  const float* eb4 = (const float*)d_in[8];
    const float* ew5 = (const float*)d_in[9];  const float* eb5 = (const float*)d_in[10];
    const float* dw1 = (const float*)d_in[11]; const float* db1 = (const float*)d_in[12];
    const float* dw2 = (const float*)d_in[13]; const float* db2 = (const float*)d_in[14];
    const float* dw3 = (const float*)d_in[15]; const float* db3 = (const float*)d_in[16];
    const float* dw4 = (const float*)d_in[17]; const float* db4 = (const float*)d_in[18];
    const float* cb  = (const float*)d_in[19];
    float* out = (float*)d_out;

    const int B = in_sizes[0] / (256 * 256);   // 64
    const int N = B * 900;

    char* ws = (char*)d_ws;
    float* Abuf = (float*)(ws + 0);
    unsigned long long* keys = (unsigned long long*)(ws + (34u << 20));
    float* Bbuf = (float*)(ws + (36u << 20));
    float* hcbn = (float*)(ws + (53u << 20));
    float* loss = (float*)(ws + (53u << 20) + 4096);

    hipMemsetAsync(loss, 0, sizeof(float), stream);
    hipMemsetAsync(keys, 0xFF, (size_t)N * 8, stream);
    cbnorm_k<<<2, 256, 0, stream>>>(cb, hcbn);

    // ---- encoder ----
    conv_k<1, 8, 8, 4, 2, 0, true><<<dim3(nblk(127 * 127), 1, B), 256, 0, stream>>>(
        x, ew1, eb1, Abuf, 256, 256, 127, 127);
    conv_k<8, 16, 8, 4, 2, 0, true><<<dim3(nblk(62 * 62), 2, B), 256, 0, stream>>>(
        Abuf, ew2, eb2, Bbuf, 127, 127, 62, 62);
    conv_k<16, 32, 8, 4, 2, 0, true><<<dim3(nblk(900), 4, B), 256, 0, stream>>>(
        Bbuf, ew3, eb3, Abuf, 62, 62, 30, 30);
    conv_k<32, 32, 8, 3, 1, 1, true><<<dim3(nblk(900), 4, B), 256, 0, stream>>>(
        Abuf, ew4, eb4, Bbuf, 30, 30, 30, 30);
    conv_k<32, 64, 8, 1, 1, 0, true><<<dim3(nblk(900), 8, B), 256, 0, stream>>>(
        Bbuf, ew5, eb5, Abuf, 30, 30, 30, 30);

    // ---- VQ: lat=A -> keys -> z=B ----
    vq_argmin_k<<<dim3(nblk(N), 4), 256, 0, stream>>>(Abuf, cb, hcbn, keys, B, 900);
    vq_finalize_k<<<nblk(N), 256, 0, stream>>>(Abuf, cb, keys, Bbuf, loss, B, 900);

    // ---- decoder ----
    conv_k<64, 32, 8, 3, 1, 1, true><<<dim3(nblk(900), 4, B), 256, 0, stream>>>(
        Bbuf, dw1, db1, Abuf, 30, 30, 30, 30);
    {   // d2: [B,32,30,30] -> [B,16,63,63]
        int nb2 = (32 * 32 + 255) / 256;   // 4
        convt_k<32, 16, 8, true, false><<<dim3(4 * nb2, 2, B), 256, 0, stream>>>(
            Abuf, dw2, db2, Bbuf, 30, 30, 63, 63, nb2);
    }
    {   // d3: [B,16,63,63] -> [B,8,129,129]
        int nb2 = (65 * 65 + 255) / 256;   // 17
        convt_k<16, 8, 8, true, false><<<dim3(4 * nb2, 1, B), 256, 0, stream>>>(
            Bbuf, dw3, db3, Abuf, 63, 63, 129, 129, nb2);
    }
    {   // d4: [B,8,129,129] -> [B,1,260,260] + tanh
        int nb2 = (130 * 130 + 255) / 256; // 67
        convt_k<8, 1, 1, false, true><<<dim3(4 * nb2, 1, B), 256, 0, stream>>>(
            Abuf, dw4, db4, out, 129, 129, 260, 260, nb2);
    }

    loss_final_k<<<1, 64, 0, stream>>>(loss, out + (out_size - 1),
                                       1.0f / ((float)N * 64.f));
}

// Round 4
// 553.911 us; speedup vs baseline: 2.3629x; 1.5433x over previous
//
#include <hip/hip_runtime.h>
#include <hip/hip_bf16.h>
#include <math.h>

#define LRELU 0.01f

// ============ weight transposers ============
// fwd: src [co][ci][t] -> dst [ci][t][co]
__global__ __launch_bounds__(256)
void wt_fwd_k(const float* __restrict__ src, float* __restrict__ dst,
              int CIN, int COUT, int KK) {
    int i = blockIdx.x * 256 + threadIdx.x;
    int total = CIN * COUT * KK;
    if (i >= total) return;
    int co = i / (CIN * KK);
    int r  = i - co * CIN * KK;
    int ci = r / KK;
    int t  = r - ci * KK;
    dst[(ci * KK + t) * COUT + co] = src[i];
}
// convT: src [ci][co][t] -> dst [t][ci][co]
__global__ __launch_bounds__(256)
void wt_tr_k(const float* __restrict__ src, float* __restrict__ dst,
             int CIN, int COUT, int KK) {
    int i = blockIdx.x * 256 + threadIdx.x;
    int total = CIN * COUT * KK;
    if (i >= total) return;
    int ci = i / (COUT * KK);
    int r  = i - ci * COUT * KK;
    int co = r / KK;
    int t  = r - co * KK;
    dst[(t * CIN + ci) * COUT + co] = src[i];
}

// ============ forward conv, transposed weights ============
// grid: (NBI [+1 boundary block if PAD>0], COUT/CO_BLK, B)
// interior blocks: uniform, no bounds checks. boundary block: checked, covers
// the pad-affected frame (2*Wout + 2*(Hout-2) pixels, fits in 256 threads).
template<int CIN, int COUT, int CO_BLK, int K, int STRIDE, int PAD, bool RELU>
__global__ __launch_bounds__(256)
void convf_k(const float* __restrict__ in, const float* __restrict__ wt,
             const float* __restrict__ bias, float* __restrict__ out,
             int Hin, int Win, int Hout, int Wout) {
    const int HW = Hout * Wout;
    const int cog = blockIdx.y, b = blockIdx.z;
    float acc[CO_BLK];
#pragma unroll
    for (int c = 0; c < CO_BLK; c++) acc[c] = bias[cog * CO_BLK + c];
    const float* inb0 = in + (size_t)(b * CIN) * Hin * Win;
    const float* wtg  = wt + cog * CO_BLK;

    int oh, ow;
    bool checked = false;
    if (PAD == 0 || (int)blockIdx.x < (int)gridDim.x - 1) {
        const int WE  = Wout - 2 * PAD;
        const int NPX = (Hout - 2 * PAD) * WE;
        int p = blockIdx.x * 256 + threadIdx.x;
        if (p >= NPX) return;
        int r = p / WE;
        oh = PAD + r; ow = PAD + p - r * WE;
    } else {
        const int Nb = 2 * Wout + 2 * (Hout - 2);
        int t = threadIdx.x;
        if (t >= Nb) return;
        checked = true;
        if (t < Wout)          { oh = 0;        ow = t; }
        else if (t < 2 * Wout) { oh = Hout - 1; ow = t - Wout; }
        else { int r = t - 2 * Wout; oh = 1 + (r >> 1); ow = (r & 1) ? Wout - 1 : 0; }
    }
    const int ihb = oh * STRIDE - PAD, iwb = ow * STRIDE - PAD;

    if (!checked) {
        const float* inb = inb0 + (size_t)ihb * Win + iwb;
        for (int ci = 0; ci < CIN; ci++) {
            float xin[K * K];
#pragma unroll
            for (int kh = 0; kh < K; kh++)
#pragma unroll
                for (int kw = 0; kw < K; kw++)
                    xin[kh * K + kw] = inb[((size_t)ci * Hin + kh) * Win + kw];
            const float* wr = wtg + (size_t)(ci * K * K) * COUT;
#pragma unroll
            for (int t = 0; t < K * K; t++)
#pragma unroll
                for (int c = 0; c < CO_BLK; c++)
                    acc[c] = fmaf(xin[t], wr[(size_t)t * COUT + c], acc[c]);
        }
    } else {
        for (int ci = 0; ci < CIN; ci++) {
#pragma unroll
            for (int kh = 0; kh < K; kh++) {
                int ih = ihb + kh;
                if (ih < 0 || ih >= Hin) continue;
#pragma unroll
                for (int kw = 0; kw < K; kw++) {
                    int iw = iwb + kw;
                    if (iw < 0 || iw >= Win) continue;
                    float x = inb0[((size_t)ci * Hin + ih) * Win + iw];
                    const float* wr = wtg + (size_t)((ci * K + kh) * K + kw) * COUT;
#pragma unroll
                    for (int c = 0; c < CO_BLK; c++)
                        acc[c] = fmaf(x, wr[c], acc[c]);
                }
            }
        }
    }
    float* outb = out + ((size_t)(b * COUT) + cog * CO_BLK) * HW + oh * Wout + ow;
#pragma unroll
    for (int c = 0; c < CO_BLK; c++) {
        float v = acc[c];
        if (RELU) v = (v >= 0.f) ? v : LRELU * v;
        outb[(size_t)c * HW] = v;
    }
}

// ============ transpose conv K=4 S=2, parity grid, transposed weights =======
// wt layout: [kh*4+kw][ci][co]
template<int CIN, int COUT, int CO_BLK, bool RELU, bool DO_TANH>
__global__ __launch_bounds__(256)
void convt_k(const float* __restrict__ in, const float* __restrict__ wt,
             const float* __restrict__ bias, float* __restrict__ out,
             int Hin, int Win, int Hout, int Wout, int nb2) {
    const int HW = Hout * Wout;
    int cls = blockIdx.x / nb2;
    int blk = blockIdx.x - cls * nb2;
    int py = cls & 1, px = cls >> 1;
    int H2 = (Hout - py + 1) >> 1;
    int W2 = (Wout - px + 1) >> 1;
    int idx = blk * 256 + threadIdx.x;
    if (idx >= H2 * W2) return;
    int oh2 = idx / W2, ow2 = idx - oh2 * W2;
    int oh = oh2 * 2 + py, ow = ow2 * 2 + px;
    int cog = blockIdx.y, b = blockIdx.z;

    float acc[CO_BLK];
#pragma unroll
    for (int c = 0; c < CO_BLK; c++) acc[c] = bias[cog * CO_BLK + c];

    const float* inb = in + (size_t)(b * CIN) * Hin * Win;
#pragma unroll
    for (int a = 0; a < 2; a++) {
        int ih = oh2 - a;
        bool vy = (ih >= 0) && (ih < Hin);
#pragma unroll
        for (int q = 0; q < 2; q++) {
            int iw = ow2 - q;
            bool v = vy && (iw >= 0) && (iw < Win);
            int kh = py + 2 * a, kw = px + 2 * q;
            const float* wr = wt + (size_t)((kh * 4 + kw) * CIN) * COUT + cog * CO_BLK;
            for (int ci = 0; ci < CIN; ci++) {
                float x = v ? inb[((size_t)ci * Hin + ih) * Win + iw] : 0.f;
#pragma unroll
                for (int c = 0; c < CO_BLK; c++)
                    acc[c] = fmaf(x, wr[(size_t)ci * COUT + c], acc[c]);
            }
        }
    }
    float* outb = out + ((size_t)(b * COUT) + cog * CO_BLK) * HW + oh * Wout + ow;
#pragma unroll
    for (int c = 0; c < CO_BLK; c++) {
        float v = acc[c];
        if (RELU) v = (v >= 0.f) ? v : LRELU * v;
        if (DO_TANH) v = tanhf(v);
        outb[(size_t)c * HW] = v;
    }
}

// ============ codebook half-norms ============
__global__ __launch_bounds__(256)
void cbnorm_k(const float* __restrict__ cb, float* __restrict__ hcbn) {
    int k = blockIdx.x * 256 + threadIdx.x;
    if (k >= 512) return;
    const float* c = cb + k * 64;
    float s = 0.f;
#pragma unroll
    for (int d = 0; d < 64; d++) s = fmaf(c[d], c[d], s);
    hcbn[k] = 0.5f * s;
}

// ============ VQ stage 1: blocked argmin ============
__global__ __launch_bounds__(256)
void vq_argmin_k(const float* __restrict__ lat, const float* __restrict__ cb,
                 const float* __restrict__ hcbn,
                 unsigned long long* __restrict__ keys, int B, int HW) {
    __shared__ float4 scb4[1024];   // 64 codes x 64 dims = 16KB
    __shared__ float  shn[64];
    const int tid = threadIdx.x;
    const int dq  = tid & 3;
    const int pg  = tid >> 2;
    const int q   = blockIdx.y;
    const int N   = B * HW;
    const int posbase = blockIdx.x * 256;

    float l[4][16];
    int   pidx[4];
    bool  valid[4];
#pragma unroll
    for (int j = 0; j < 4; j++) {
        int pos = posbase + pg + 64 * j;
        pidx[j] = pos;
        valid[j] = pos < N;
        if (valid[j]) {
            int b = pos / HW, p = pos - b * HW;
            const float* lb = lat + ((size_t)b * 64 + dq * 16) * HW + p;
#pragma unroll
            for (int i = 0; i < 16; i++) l[j][i] = lb[i * HW];
        } else {
#pragma unroll
            for (int i = 0; i < 16; i++) l[j][i] = 0.f;
        }
    }

    float best[4] = {3.4e38f, 3.4e38f, 3.4e38f, 3.4e38f};
    int   bi[4]   = {0, 0, 0, 0};

    for (int c = 0; c < 2; c++) {
        const int kbase = q * 128 + c * 64;
        const float4* src = (const float4*)(cb + (size_t)kbase * 64);
        __syncthreads();
#pragma unroll
        for (int i = 0; i < 4; i++) scb4[tid + 256 * i] = src[tid + 256 * i];
        if (tid < 64) shn[tid] = hcbn[kbase + tid];
        __syncthreads();

#pragma unroll 2
        for (int k0 = 0; k0 < 64; k0++) {
            float4 c0 = scb4[k0 * 16 + dq * 4 + 0];
            float4 c1 = scb4[k0 * 16 + dq * 4 + 1];
            float4 c2 = scb4[k0 * 16 + dq * 4 + 2];
            float4 c3 = scb4[k0 * 16 + dq * 4 + 3];
            float hn = shn[k0];
#pragma unroll
            for (int j = 0; j < 4; j++) {
                float dot = 0.f;
                dot = fmaf(l[j][0],  c0.x, dot); dot = fmaf(l[j][1],  c0.y, dot);
                dot = fmaf(l[j][2],  c0.z, dot); dot = fmaf(l[j][3],  c0.w, dot);
                dot = fmaf(l[j][4],  c1.x, dot); dot = fmaf(l[j][5],  c1.y, dot);
                dot = fmaf(l[j][6],  c1.z, dot); dot = fmaf(l[j][7],  c1.w, dot);
                dot = fmaf(l[j][8],  c2.x, dot); dot = fmaf(l[j][9],  c2.y, dot);
                dot = fmaf(l[j][10], c2.z, dot); dot = fmaf(l[j][11], c2.w, dot);
                dot = fmaf(l[j][12], c3.x, dot); dot = fmaf(l[j][13], c3.y, dot);
                dot = fmaf(l[j][14], c3.z, dot); dot = fmaf(l[j][15], c3.w, dot);
                float full = dot + __shfl_xor(dot, 1);
                full += __shfl_xor(full, 2);
                float score = hn - full;
                if (score < best[j]) { best[j] = score; bi[j] = kbase + k0; }
            }
        }
    }

    if (dq == 0) {
#pragma unroll
        for (int j = 0; j < 4; j++) {
            if (!valid[j]) continue;
            unsigned u = __float_as_uint(best[j]);
            u = ((int)u < 0) ? ~u : (u | 0x80000000u);
            unsigned long long key = ((unsigned long long)u << 32) | (unsigned)bi[j];
            atomicMin(&keys[pidx[j]], key);
        }
    }
}

// ============ VQ stage 2: gather winner, write z, loss ============
__global__ __launch_bounds__(256)
void vq_finalize_k(const float* __restrict__ lat, const float* __restrict__ cb,
                   const unsigned long long* __restrict__ keys,
                   float* __restrict__ z, float* __restrict__ loss_acc,
                   int B, int HW) {
    int gid = blockIdx.x * 256 + threadIdx.x;
    const int N = B * HW;
    float myloss = 0.f;
    if (gid < N) {
        int b = gid / HW, p = gid - b * HW;
        int idx = (int)(unsigned)(keys[gid] & 0xFFFFFFFFull);
        const float4* crow = (const float4*)(cb + (size_t)idx * 64);
        const float* lrow = lat + (size_t)b * 64 * HW + p;
        float*       zrow = z   + (size_t)b * 64 * HW + p;
#pragma unroll
        for (int i = 0; i < 16; i++) {
            float4 cv = crow[i];
            float lv0 = lrow[(4 * i + 0) * HW];
            float lv1 = lrow[(4 * i + 1) * HW];
            float lv2 = lrow[(4 * i + 2) * HW];
            float lv3 = lrow[(4 * i + 3) * HW];
            zrow[(4 * i + 0) * HW] = cv.x;
            zrow[(4 * i + 1) * HW] = cv.y;
            zrow[(4 * i + 2) * HW] = cv.z;
            zrow[(4 * i + 3) * HW] = cv.w;
            float d0 = cv.x - lv0, d1 = cv.y - lv1, d2 = cv.z - lv2, d3 = cv.w - lv3;
            myloss = fmaf(d0, d0, myloss);
            myloss = fmaf(d1, d1, myloss);
            myloss = fmaf(d2, d2, myloss);
            myloss = fmaf(d3, d3, myloss);
        }
    }
    __shared__ float red[256];
    red[threadIdx.x] = myloss;
    __syncthreads();
    for (int s = 128; s > 0; s >>= 1) {
        if ((int)threadIdx.x < s) red[threadIdx.x] += red[threadIdx.x + s];
        __syncthreads();
    }
    if (threadIdx.x == 0) atomicAdd(loss_acc, red[0]);
}

__global__ void loss_final_k(const float* __restrict__ loss_acc,
                             float* __restrict__ out_last, float inv_n) {
    if (blockIdx.x == 0 && threadIdx.x == 0)
        out_last[0] = 1.25f * loss_acc[0] * inv_n;
}

static inline int nblk(long long total) { return (int)((total + 255) / 256); }

extern "C" void kernel_launch(void* const* d_in, const int* in_sizes, int n_in,
                              void* d_out, int out_size, void* d_ws, size_t ws_size,
                              hipStream_t stream) {
    const float* x   = (const float*)d_in[0];
    const float* ew1 = (const float*)d_in[1];  const float* eb1 = (const float*)d_in[2];
    const float* ew2 = (const float*)d_in[3];  const float* eb2 = (const float*)d_in[4];
    const float* ew3 = (const float*)d_in[5];  const float* eb3 = (const float*)d_in[6];
    const float* ew4 = (const float*)d_in[7];  const float* eb4 = (const float*)d_in[8];
    const float* ew5 = (const float*)d_in[9];  const float* eb5 = (const float*)d_in[10];
    const float* dw1 = (const float*)d_in[11]; const float* db1 = (const float*)d_in[12];
    const float* dw2 = (const float*)d_in[13]; const float* db2 = (const float*)d_in[14];
    const float* dw3 = (const float*)d_in[15]; const float* db3 = (const float*)d_in[16];
    const float* dw4 = (const float*)d_in[17]; const float* db4 = (const float*)d_in[18];
    const float* cb  = (const float*)d_in[19];
    float* out = (float*)d_out;

    const int B = in_sizes[0] / (256 * 256);   // 64
    const int N = B * 900;

    char* ws = (char*)d_ws;
    float* Abuf = (float*)(ws + 0);
    unsigned long long* keys = (unsigned long long*)(ws + (34u << 20));
    float* Bbuf = (float*)(ws + (36u << 20));
    float* hcbn = (float*)(ws + (53u << 20));
    float* loss = (float*)(ws + (53u << 20) + 4096);
    float* wtb  = (float*)(ws + (53u << 20) + 8192);
    float* ew1t = wtb;          // 128
    float* ew2t = wtb + 128;    // 2048
    float* ew3t = wtb + 2176;   // 8192
    float* ew4t = wtb + 10368;  // 9216
    float* ew5t = wtb + 19584;  // 2048
    float* dw1t = wtb + 21632;  // 18432
    float* dw2t = wtb + 40064;  // 8192
    float* dw3t = wtb + 48256;  // 2048
    float* dw4t = wtb + 50304;  // 128

    hipMemsetAsync(loss, 0, sizeof(float), stream);
    hipMemsetAsync(keys, 0xFF, (size_t)N * 8, stream);
    cbnorm_k<<<2, 256, 0, stream>>>(cb, hcbn);

    // weight transposes (tiny)
    wt_fwd_k<<<nblk(128),   256, 0, stream>>>(ew1, ew1t, 1, 8, 16);
    wt_fwd_k<<<nblk(2048),  256, 0, stream>>>(ew2, ew2t, 8, 16, 16);
    wt_fwd_k<<<nblk(8192),  256, 0, stream>>>(ew3, ew3t, 16, 32, 16);
    wt_fwd_k<<<nblk(9216),  256, 0, stream>>>(ew4, ew4t, 32, 32, 9);
    wt_fwd_k<<<nblk(2048),  256, 0, stream>>>(ew5, ew5t, 32, 64, 1);
    wt_fwd_k<<<nblk(18432), 256, 0, stream>>>(dw1, dw1t, 64, 32, 9);
    wt_tr_k <<<nblk(8192),  256, 0, stream>>>(dw2, dw2t, 32, 16, 16);
    wt_tr_k <<<nblk(2048),  256, 0, stream>>>(dw3, dw3t, 16, 8, 16);
    wt_tr_k <<<nblk(128),   256, 0, stream>>>(dw4, dw4t, 8, 1, 16);

    // ---- encoder ----
    convf_k<1, 8, 8, 4, 2, 0, true><<<dim3(nblk(127 * 127), 1, B), 256, 0, stream>>>(
        x, ew1t, eb1, Abuf, 256, 256, 127, 127);
    convf_k<8, 16, 16, 4, 2, 0, true><<<dim3(nblk(62 * 62), 1, B), 256, 0, stream>>>(
        Abuf, ew2t, eb2, Bbuf, 127, 127, 62, 62);
    convf_k<16, 32, 16, 4, 2, 0, true><<<dim3(nblk(900), 2, B), 256, 0, stream>>>(
        Bbuf, ew3t, eb3, Abuf, 62, 62, 30, 30);
    convf_k<32, 32, 16, 3, 1, 1, true><<<dim3(nblk(28 * 28) + 1, 2, B), 256, 0, stream>>>(
        Abuf, ew4t, eb4, Bbuf, 30, 30, 30, 30);
    convf_k<32, 64, 16, 1, 1, 0, true><<<dim3(nblk(900), 4, B), 256, 0, stream>>>(
        Bbuf, ew5t, eb5, Abuf, 30, 30, 30, 30);

    // ---- VQ: lat=A -> keys -> z=B ----
    vq_argmin_k<<<dim3(nblk(N), 4), 256, 0, stream>>>(Abuf, cb, hcbn, keys, B, 900);
    vq_finalize_k<<<nblk(N), 256, 0, stream>>>(Abuf, cb, keys, Bbuf, loss, B, 900);

    // ---- decoder ----
    convf_k<64, 32, 16, 3, 1, 1, true><<<dim3(nblk(28 * 28) + 1, 2, B), 256, 0, stream>>>(
        Bbuf, dw1t, db1, Abuf, 30, 30, 30, 30);
    {   // d2: [B,32,30,30] -> [B,16,63,63]
        int nb2 = (32 * 32 + 255) / 256;   // 4
        convt_k<32, 16, 16, true, false><<<dim3(4 * nb2, 1, B), 256, 0, stream>>>(
            Abuf, dw2t, db2, Bbuf, 30, 30, 63, 63, nb2);
    }
    {   // d3: [B,16,63,63] -> [B,8,129,129]
        int nb2 = (65 * 65 + 255) / 256;   // 17
        convt_k<16, 8, 8, true, false><<<dim3(4 * nb2, 1, B), 256, 0, stream>>>(
            Bbuf, dw3t, db3, Abuf, 63, 63, 129, 129, nb2);
    }
    {   // d4: [B,8,129,129] -> [B,1,260,260] + tanh
        int nb2 = (130 * 130 + 255) / 256; // 67
        convt_k<8, 1, 1, false, true><<<dim3(4 * nb2, 1, B), 256, 0, stream>>>(
            Abuf, dw4t, db4, out, 129, 129, 260, 260, nb2);
    }

    loss_final_k<<<1, 64, 0, stream>>>(loss, out + (out_size - 1),
                                       1.0f / ((float)N * 64.f));
}

// Round 5
// 505.354 us; speedup vs baseline: 2.5899x; 1.0961x over previous
//
#include <hip/hip_runtime.h>
#include <hip/hip_bf16.h>
#include <math.h>

#define LRELU 0.01f

// ======================= fused weight transposes =======================
__device__ __forceinline__ void wfwd(const float* s, float* d, int CIN, int COUT,
                                     int KK, int i) {
    int co = i / (CIN * KK); int r = i - co * CIN * KK;
    int ci = r / KK; int t = r - ci * KK;
    d[(ci * KK + t) * COUT + co] = s[i];
}
__device__ __forceinline__ void wtr(const float* s, float* d, int CIN, int COUT,
                                    int KK, int i) {
    int ci = i / (COUT * KK); int r = i - ci * COUT * KK;
    int co = r / KK; int t = r - co * KK;
    d[(t * CIN + ci) * COUT + co] = s[i];
}
__global__ __launch_bounds__(256)
void wt_all_k(const float* e1, const float* e2, const float* e3, const float* e4,
              const float* e5, const float* d1, const float* d2, const float* d3,
              const float* d4, float* w) {
    int i = blockIdx.x * 256 + threadIdx.x;
    if      (i < 128)   wfwd(e1, w + 0,     1,  8, 16, i);
    else if (i < 2176)  wfwd(e2, w + 128,   8, 16, 16, i - 128);
    else if (i < 10368) wfwd(e3, w + 2176, 16, 32, 16, i - 2176);
    else if (i < 19584) wfwd(e4, w + 10368, 32, 32, 9, i - 10368);
    else if (i < 21632) wfwd(e5, w + 19584, 32, 64, 1, i - 19584);
    else if (i < 40064) wfwd(d1, w + 21632, 64, 32, 9, i - 21632);
    else if (i < 48256) wtr (d2, w + 40064, 32, 16, 16, i - 40064);
    else if (i < 50304) wtr (d3, w + 48256, 16,  8, 16, i - 48256);
    else if (i < 50432) wtr (d4, w + 50304,  8,  1, 16, i - 50304);
}

// ======================= zero helpers =======================
// zero frame of [64,C,32,32] planes (rows 0,31 + cols 0,31)
__global__ __launch_bounds__(256)
void zframe_k(float* p, int C) {
    int i = blockIdx.x * 256 + threadIdx.x;
    int total = 64 * C * 124;
    if (i >= total) return;
    int pl = i / 124, s = i - pl * 124;
    int r, c;
    if (s < 32)      { r = 0;  c = s; }
    else if (s < 64) { r = 31; c = s - 32; }
    else { int u = s - 64; r = 1 + (u >> 1); c = (u & 1) * 31; }
    p[(size_t)pl * 1024 + r * 32 + c] = 0.f;
}
// zero side cols of d2out [64,16,63,66]{0,64,65} and d3out [64,8,129,132]{0,130,131}
__global__ __launch_bounds__(256)
void zsides_k(float* d2o, float* d3o) {
    int i = blockIdx.x * 256 + threadIdx.x;
    const int N2 = 64 * 16 * 63 * 3;
    const int N3 = 64 * 8 * 129 * 3;
    if (i < N2) {
        int pl = i / 189, u = i - pl * 189;
        int r = u / 3, c3 = u - r * 3;
        int col = (c3 == 0) ? 0 : 63 + c3;
        d2o[((size_t)pl * 63 + r) * 66 + col] = 0.f;
    } else if (i < N2 + N3) {
        int j = i - N2;
        int pl = j / 387, u = j - pl * 387;
        int r = u / 3, c3 = u - r * 3;
        int col = (c3 == 0) ? 0 : 129 + c3;
        d3o[((size_t)pl * 129 + r) * 132 + col] = 0.f;
    }
}

// ======================= k4 s2 forward conv, 2px/thread =======================
// in stride ISTR (>= Win, f4-aligned), out: plane OPLANE, stride OSTR, offset OPAD
template<int CIN, int COUT, int CO_BLK, int HIN, int ISTR, int HOUT, int WOUT,
         int OPLANE, int OSTR, int OPAD, int CB, int RB>
__global__ __launch_bounds__(256)
void convs2_k(const float* __restrict__ in, const float* __restrict__ wt,
              const float* __restrict__ bias, float* __restrict__ out) {
    const int bx = blockIdx.x;
    const int cbi = bx / RB, rb = bx - cbi * RB;
    const int tx = threadIdx.x & 15, ty = threadIdx.x >> 4;
    const int cog = blockIdx.y, b = blockIdx.z;
    const int ow0 = (cbi * 16 + tx) * 2;
    const int oh  = rb * 16 + ty;
    if (oh >= HOUT || ow0 >= WOUT) return;
    const bool p1v = (ow0 + 1) < WOUT;

    float acc[CO_BLK][2];
#pragma unroll
    for (int c = 0; c < CO_BLK; c++) {
        float bv = bias[cog * CO_BLK + c];
        acc[c][0] = bv; acc[c][1] = bv;
    }
    const float* inb = in + ((size_t)(b * CIN) * HIN + oh * 2) * ISTR + ow0 * 2;
    const float* wtg = wt + cog * CO_BLK;
#pragma unroll 2
    for (int ci = 0; ci < CIN; ci++) {
        const float* r = inb + (size_t)ci * HIN * ISTR;
        float4 a4[4]; float2 b2[4];
#pragma unroll
        for (int kh = 0; kh < 4; kh++) {
            a4[kh] = *(const float4*)(r + kh * ISTR);
            b2[kh] = p1v ? *(const float2*)(r + kh * ISTR + 4) : make_float2(0.f, 0.f);
        }
        const float* wr = wtg + (size_t)ci * 16 * COUT;
#pragma unroll
        for (int kh = 0; kh < 4; kh++) {
            float x0[4] = {a4[kh].x, a4[kh].y, a4[kh].z, a4[kh].w};
            float x1[4] = {a4[kh].z, a4[kh].w, b2[kh].x, b2[kh].y};
#pragma unroll
            for (int kw = 0; kw < 4; kw++) {
                const float* wv = wr + (kh * 4 + kw) * COUT;
#pragma unroll
                for (int c = 0; c < CO_BLK; c++) {
                    float wgt = wv[c];
                    acc[c][0] = fmaf(x0[kw], wgt, acc[c][0]);
                    acc[c][1] = fmaf(x1[kw], wgt, acc[c][1]);
                }
            }
        }
    }
    float* ob = out + (size_t)(b * COUT + cog * CO_BLK) * OPLANE
                    + (oh + OPAD) * OSTR + ow0 + OPAD;
#pragma unroll
    for (int c = 0; c < CO_BLK; c++) {
        float v0 = acc[c][0]; v0 = (v0 >= 0.f) ? v0 : LRELU * v0;
        ob[(size_t)c * OPLANE] = v0;
        if (p1v) {
            float v1 = acc[c][1]; v1 = (v1 >= 0.f) ? v1 : LRELU * v1;
            ob[(size_t)c * OPLANE + 1] = v1;
        }
    }
}

// ======================= k3 s1 p1 conv on padded [B,C,32,32] input ==========
template<int CIN, int COUT, int CO_BLK, int OPLANE, int OSTR, int OPADH, int OPADV,
         bool ZSIDE>
__global__ __launch_bounds__(256)
void conv3_k(const float* __restrict__ in, const float* __restrict__ wt,
             const float* __restrict__ bias, float* __restrict__ out) {
    const int rb = blockIdx.x;
    const int tx = threadIdx.x & 15, ty = threadIdx.x >> 4;
    const int cog = blockIdx.y, b = blockIdx.z;
    const int r = rb * 16 + ty;
    if (r >= 30) return;
    const int ow0 = tx * 2;
    if (tx == 15) {
        if (ZSIDE) {
#pragma unroll
            for (int c = 0; c < CO_BLK; c++) {
                float* base = out + (size_t)(b * COUT + cog * CO_BLK + c) * OPLANE
                                  + (r + OPADV) * OSTR;
                base[0] = 0.f; base[31] = 0.f; base[32] = 0.f;
            }
        }
        return;
    }
    float acc[CO_BLK][2];
#pragma unroll
    for (int c = 0; c < CO_BLK; c++) {
        float bv = bias[cog * CO_BLK + c];
        acc[c][0] = bv; acc[c][1] = bv;
    }
    const float* inb = in + ((size_t)(b * CIN) * 32 + r) * 32 + ow0;
    const float* wtg = wt + cog * CO_BLK;
#pragma unroll 2
    for (int ci = 0; ci < CIN; ci++) {
        const float* rr = inb + (size_t)ci * 1024;
        float2 A[3], Bv[3];
#pragma unroll
        for (int kh = 0; kh < 3; kh++) {
            A[kh]  = *(const float2*)(rr + kh * 32);
            Bv[kh] = *(const float2*)(rr + kh * 32 + 2);
        }
        const float* wr = wtg + (size_t)ci * 9 * COUT;
#pragma unroll
        for (int kh = 0; kh < 3; kh++) {
            float x0[3] = {A[kh].x, A[kh].y, Bv[kh].x};
            float x1[3] = {A[kh].y, Bv[kh].x, Bv[kh].y};
#pragma unroll
            for (int kw = 0; kw < 3; kw++) {
                const float* wv = wr + (kh * 3 + kw) * COUT;
#pragma unroll
                for (int c = 0; c < CO_BLK; c++) {
                    float wgt = wv[c];
                    acc[c][0] = fmaf(x0[kw], wgt, acc[c][0]);
                    acc[c][1] = fmaf(x1[kw], wgt, acc[c][1]);
                }
            }
        }
    }
    float* ob = out + (size_t)(b * COUT + cog * CO_BLK) * OPLANE
                    + (r + OPADV) * OSTR + ow0 + OPADH;
#pragma unroll
    for (int c = 0; c < CO_BLK; c++) {
        float v0 = acc[c][0]; v0 = (v0 >= 0.f) ? v0 : LRELU * v0;
        float v1 = acc[c][1]; v1 = (v1 >= 0.f) ? v1 : LRELU * v1;
        ob[(size_t)c * OPLANE] = v0;
        ob[(size_t)c * OPLANE + 1] = v1;
    }
}

// ======================= 1x1 conv on padded planes, 4px/thread ==============
template<int CIN, int COUT, int CO_BLK>
__global__ __launch_bounds__(256)
void conv1_k(const float* __restrict__ in, const float* __restrict__ wt,
             const float* __restrict__ bias, float* __restrict__ out) {
    const int px4 = threadIdx.x * 4;
    const int cog = blockIdx.x, b = blockIdx.z;
    float acc[CO_BLK][4];
#pragma unroll
    for (int c = 0; c < CO_BLK; c++) {
        float bv = bias[cog * CO_BLK + c];
        acc[c][0] = bv; acc[c][1] = bv; acc[c][2] = bv; acc[c][3] = bv;
    }
#pragma unroll 4
    for (int ci = 0; ci < CIN; ci++) {
        float4 x = *(const float4*)(in + (size_t)(b * CIN + ci) * 1024 + px4);
        const float* wr = wt + ci * COUT + cog * CO_BLK;
#pragma unroll
        for (int c = 0; c < CO_BLK; c++) {
            float wgt = wr[c];
            acc[c][0] = fmaf(x.x, wgt, acc[c][0]);
            acc[c][1] = fmaf(x.y, wgt, acc[c][1]);
            acc[c][2] = fmaf(x.z, wgt, acc[c][2]);
            acc[c][3] = fmaf(x.w, wgt, acc[c][3]);
        }
    }
#pragma unroll
    for (int c = 0; c < CO_BLK; c++) {
        float4 v;
        v.x = (acc[c][0] >= 0.f) ? acc[c][0] : LRELU * acc[c][0];
        v.y = (acc[c][1] >= 0.f) ? acc[c][1] : LRELU * acc[c][1];
        v.z = (acc[c][2] >= 0.f) ? acc[c][2] : LRELU * acc[c][2];
        v.w = (acc[c][3] >= 0.f) ? acc[c][3] : LRELU * acc[c][3];
        *(float4*)(out + (size_t)(b * COUT + cog * CO_BLK + c) * 1024 + px4) = v;
    }
}

// ======================= convT k4 s2, parity classes, 2px/thread ============
// in: padded-width layout, left pad 1 (zeroed), stride ISTR; taps per class = 4.
template<int CIN, int COUT, int CO_BLK, int HIN, int ISTR, int HOUT, int WOUT,
         int OPLANE, int OSTR, int OPADH, int TX, int CB, int RB, bool DO_TANH>
__global__ __launch_bounds__(256)
void convt2_k(const float* __restrict__ in, const float* __restrict__ wt,
              const float* __restrict__ bias, float* __restrict__ out) {
    const int x = blockIdx.x;
    const int cls = x / (CB * RB);
    const int rem = x - cls * (CB * RB);
    const int cb = rem / RB, rb = rem - cb * RB;
    const int py = cls & 1, px = cls >> 1;
    const int H2 = (HOUT - py + 1) >> 1;
    const int W2 = (WOUT - px + 1) >> 1;
    const int TY = 256 / TX;
    const int tx = threadIdx.x % TX, ty = threadIdx.x / TX;
    const int o0 = (cb * TX + tx) * 2;
    const int oh2 = rb * TY + ty;
    if (oh2 >= H2 || o0 >= W2) return;
    const bool p1v = (o0 + 1) < W2;
    const int cog = blockIdx.y, b = blockIdx.z;

    float acc[CO_BLK][2];
#pragma unroll
    for (int c = 0; c < CO_BLK; c++) {
        float bv = bias[cog * CO_BLK + c];
        acc[c][0] = bv; acc[c][1] = bv;
    }
#pragma unroll
    for (int a = 0; a < 2; a++) {
        int ih = oh2 - a;
        bool rv = (ih >= 0) && (ih < HIN);
        int kh = py + 2 * a;
        const float* w0b = wt + (size_t)((kh * 4 + px) * CIN) * COUT + cog * CO_BLK;
        const float* w1b = wt + (size_t)((kh * 4 + px + 2) * CIN) * COUT + cog * CO_BLK;
        const float* rowp = in + ((size_t)(b * CIN) * HIN + ih) * ISTR + o0;
#pragma unroll 2
        for (int ci = 0; ci < CIN; ci++) {
            const float* p = rowp + (size_t)ci * HIN * ISTR;
            float2 A  = rv ? *(const float2*)p : make_float2(0.f, 0.f);
            float2 Bv = (rv && p1v) ? *(const float2*)(p + 2) : make_float2(0.f, 0.f);
            const float* w0 = w0b + ci * COUT;
            const float* w1 = w1b + ci * COUT;
#pragma unroll
            for (int c = 0; c < CO_BLK; c++) {
                acc[c][0] = fmaf(A.y, w0[c], acc[c][0]);   // q=0 tap for px0
                acc[c][0] = fmaf(A.x, w1[c], acc[c][0]);   // q=1 tap for px0
                acc[c][1] = fmaf(Bv.x, w0[c], acc[c][1]);  // q=0 tap for px1
                acc[c][1] = fmaf(A.y, w1[c], acc[c][1]);   // q=1 tap for px1
            }
        }
    }
    const int oh = 2 * oh2 + py, ow = 2 * o0 + px;
    float* ob = out + (size_t)(b * COUT + cog * CO_BLK) * OPLANE + oh * OSTR + ow + OPADH;
#pragma unroll
    for (int c = 0; c < CO_BLK; c++) {
        float v0 = acc[c][0];
        if (!DO_TANH) v0 = (v0 >= 0.f) ? v0 : LRELU * v0; else v0 = tanhf(v0);
        ob[(size_t)c * OPLANE] = v0;
        if (p1v) {
            float v1 = acc[c][1];
            if (!DO_TANH) v1 = (v1 >= 0.f) ? v1 : LRELU * v1; else v1 = tanhf(v1);
            ob[(size_t)c * OPLANE + 2] = v1;
        }
    }
}

// ======================= codebook half-norms =======================
__global__ __launch_bounds__(256)
void cbnorm_k(const float* __restrict__ cb, float* __restrict__ hcbn) {
    int k = blockIdx.x * 256 + threadIdx.x;
    if (k >= 512) return;
    const float* c = cb + k * 64;
    float s = 0.f;
#pragma unroll
    for (int d = 0; d < 64; d++) s = fmaf(c[d], c[d], s);
    hcbn[k] = 0.5f * s;
}

// ======================= VQ stage 1: blocked argmin (padded lat) ============
__global__ __launch_bounds__(256)
void vq_argmin_k(const float* __restrict__ lat, const float* __restrict__ cb,
                 const float* __restrict__ hcbn,
                 unsigned long long* __restrict__ keys, int B) {
    __shared__ float4 scb4[1024];   // 64 codes x 64 dims = 16KB
    __shared__ float  shn[64];
    const int tid = threadIdx.x;
    const int dq  = tid & 3;
    const int pg  = tid >> 2;
    const int q   = blockIdx.y;
    const int N   = B * 900;
    const int posbase = blockIdx.x * 256;

    float l[4][16];
    int   pidx[4];
    bool  valid[4];
#pragma unroll
    for (int j = 0; j < 4; j++) {
        int pos = posbase + pg + 64 * j;
        pidx[j] = pos;
        valid[j] = pos < N;
        if (valid[j]) {
            int b = pos / 900, p = pos - b * 900;
            int oh = p / 30, ow = p - oh * 30;
            int pp = 33 + oh * 32 + ow;
            const float* lb = lat + ((size_t)b * 64 + dq * 16) * 1024 + pp;
#pragma unroll
            for (int i = 0; i < 16; i++) l[j][i] = lb[i * 1024];
        } else {
#pragma unroll
            for (int i = 0; i < 16; i++) l[j][i] = 0.f;
        }
    }

    float best[4] = {3.4e38f, 3.4e38f, 3.4e38f, 3.4e38f};
    int   bi[4]   = {0, 0, 0, 0};

    for (int c = 0; c < 2; c++) {
        const int kbase = q * 128 + c * 64;
        const float4* src = (const float4*)(cb + (size_t)kbase * 64);
        __syncthreads();
#pragma unroll
        for (int i = 0; i < 4; i++) scb4[tid + 256 * i] = src[tid + 256 * i];
        if (tid < 64) shn[tid] = hcbn[kbase + tid];
        __syncthreads();

#pragma unroll 2
        for (int k0 = 0; k0 < 64; k0++) {
            float4 c0 = scb4[k0 * 16 + dq * 4 + 0];
            float4 c1 = scb4[k0 * 16 + dq * 4 + 1];
            float4 c2 = scb4[k0 * 16 + dq * 4 + 2];
            float4 c3 = scb4[k0 * 16 + dq * 4 + 3];
            float hn = shn[k0];
#pragma unroll
            for (int j = 0; j < 4; j++) {
                float dot = 0.f;
                dot = fmaf(l[j][0],  c0.x, dot); dot = fmaf(l[j][1],  c0.y, dot);
                dot = fmaf(l[j][2],  c0.z, dot); dot = fmaf(l[j][3],  c0.w, dot);
                dot = fmaf(l[j][4],  c1.x, dot); dot = fmaf(l[j][5],  c1.y, dot);
                dot = fmaf(l[j][6],  c1.z, dot); dot = fmaf(l[j][7],  c1.w, dot);
                dot = fmaf(l[j][8],  c2.x, dot); dot = fmaf(l[j][9],  c2.y, dot);
                dot = fmaf(l[j][10], c2.z, dot); dot = fmaf(l[j][11], c2.w, dot);
                dot = fmaf(l[j][12], c3.x, dot); dot = fmaf(l[j][13], c3.y, dot);
                dot = fmaf(l[j][14], c3.z, dot); dot = fmaf(l[j][15], c3.w, dot);
                float full = dot + __shfl_xor(dot, 1);
                full += __shfl_xor(full, 2);
                float score = hn - full;
                if (score < best[j]) { best[j] = score; bi[j] = kbase + k0; }
            }
        }
    }

    if (dq == 0) {
#pragma unroll
        for (int j = 0; j < 4; j++) {
            if (!valid[j]) continue;
            unsigned u = __float_as_uint(best[j]);
            u = ((int)u < 0) ? ~u : (u | 0x80000000u);
            unsigned long long key = ((unsigned long long)u << 32) | (unsigned)bi[j];
            atomicMin(&keys[pidx[j]], key);
        }
    }
}

// ======================= VQ stage 2: gather, write z (padded), loss =========
__global__ __launch_bounds__(256)
void vq_finalize_k(const float* __restrict__ lat, const float* __restrict__ cb,
                   const unsigned long long* __restrict__ keys,
                   float* __restrict__ z, float* __restrict__ loss_acc, int B) {
    int gid = blockIdx.x * 256 + threadIdx.x;
    const int N = B * 900;
    float myloss = 0.f;
    if (gid < N) {
        int b = gid / 900, p = gid - b * 900;
        int oh = p / 30, ow = p - oh * 30;
        int pp = 33 + oh * 32 + ow;
        int idx = (int)(unsigned)(keys[gid] & 0xFFFFFFFFull);
        const float4* crow = (const float4*)(cb + (size_t)idx * 64);
        const float* lrow = lat + (size_t)b * 64 * 1024 + pp;
        float*       zrow = z   + (size_t)b * 64 * 1024 + pp;
#pragma unroll
        for (int i = 0; i < 16; i++) {
            float4 cv = crow[i];
            float lv0 = lrow[(4 * i + 0) * 1024];
            float lv1 = lrow[(4 * i + 1) * 1024];
            float lv2 = lrow[(4 * i + 2) * 1024];
            float lv3 = lrow[(4 * i + 3) * 1024];
            zrow[(4 * i + 0) * 1024] = cv.x;
            zrow[(4 * i + 1) * 1024] = cv.y;
            zrow[(4 * i + 2) * 1024] = cv.z;
            zrow[(4 * i + 3) * 1024] = cv.w;
            float d0 = cv.x - lv0, d1 = cv.y - lv1, d2 = cv.z - lv2, d3 = cv.w - lv3;
            myloss = fmaf(d0, d0, myloss);
            myloss = fmaf(d1, d1, myloss);
            myloss = fmaf(d2, d2, myloss);
            myloss = fmaf(d3, d3, myloss);
        }
    }
    __shared__ float red[256];
    red[threadIdx.x] = myloss;
    __syncthreads();
    for (int s = 128; s > 0; s >>= 1) {
        if ((int)threadIdx.x < s) red[threadIdx.x] += red[threadIdx.x + s];
        __syncthreads();
    }
    if (threadIdx.x == 0) atomicAdd(loss_acc, red[0]);
}

__global__ void loss_final_k(const float* __restrict__ loss_acc,
                             float* __restrict__ out_last, float inv_n) {
    if (blockIdx.x == 0 && threadIdx.x == 0)
        out_last[0] = 1.25f * loss_acc[0] * inv_n;
}

static inline int nblk(long long total) { return (int)((total + 255) / 256); }

extern "C" void kernel_launch(void* const* d_in, const int* in_sizes, int n_in,
                              void* d_out, int out_size, void* d_ws, size_t ws_size,
                              hipStream_t stream) {
    const float* x   = (const float*)d_in[0];
    const float* ew1 = (const float*)d_in[1];  const float* eb1 = (const float*)d_in[2];
    const float* ew2 = (const float*)d_in[3];  const float* eb2 = (const float*)d_in[4];
    const float* ew3 = (const float*)d_in[5];  const float* eb3 = (const float*)d_in[6];
    const float* ew4 = (const float*)d_in[7];  const float* eb4 = (const float*)d_in[8];
    const float* ew5 = (const float*)d_in[9];  const float* eb5 = (const float*)d_in[10];
    const float* dw1 = (const float*)d_in[11]; const float* db1 = (const float*)d_in[12];
    const float* dw2 = (const float*)d_in[13]; const float* db2 = (const float*)d_in[14];
    const float* dw3 = (const float*)d_in[15]; const float* db3 = (const float*)d_in[16];
    const float* dw4 = (const float*)d_in[17]; const float* db4 = (const float*)d_in[18];
    const float* cb  = (const float*)d_in[19];
    float* out = (float*)d_out;

    const int B = in_sizes[0] / (256 * 256);   // 64
    const int N = B * 900;

    // workspace: A (34.9MB): e1out/e3out/lat/d1out/d3out ; B (17.1MB): e2out/e4out/z/d2out
    char* ws = (char*)d_ws;
    float* A = (float*)(ws);
    float* Bb = (float*)(ws + 34873344);
    unsigned long long* keys = (unsigned long long*)(ws + 51904512);
    float* hcbn = (float*)(ws + 52365312);
    float* loss = (float*)(ws + 52367360);
    float* wtb  = (float*)(ws + 52367616);
    float* ew1t = wtb;          float* ew2t = wtb + 128;
    float* ew3t = wtb + 2176;   float* ew4t = wtb + 10368;
    float* ew5t = wtb + 19584;  float* dw1t = wtb + 21632;
    float* dw2t = wtb + 40064;  float* dw3t = wtb + 48256;
    float* dw4t = wtb + 50304;

    hipMemsetAsync(loss, 0, sizeof(float), stream);
    hipMemsetAsync(keys, 0xFF, (size_t)N * 8, stream);
    wt_all_k<<<nblk(50432), 256, 0, stream>>>(ew1, ew2, ew3, ew4, ew5,
                                              dw1, dw2, dw3, dw4, wtb);
    cbnorm_k<<<2, 256, 0, stream>>>(cb, hcbn);

    // ---- encoder ----
    // e1: x[64,1,256,256] -> A [64,8,127,(128)]
    convs2_k<1, 8, 8, 256, 256, 127, 127, 127 * 128, 128, 0, 4, 8>
        <<<dim3(32, 1, B), 256, 0, stream>>>(x, ew1t, eb1, A);
    // e2: A -> B [64,16,62,(64)]
    convs2_k<8, 16, 16, 127, 128, 62, 62, 62 * 64, 64, 0, 2, 4>
        <<<dim3(8, 1, B), 256, 0, stream>>>(A, ew2t, eb2, Bb);
    // e3: B -> A padded [64,32,32,32]
    convs2_k<16, 32, 8, 62, 64, 30, 30, 1024, 32, 1, 1, 2>
        <<<dim3(2, 4, B), 256, 0, stream>>>(Bb, ew3t, eb3, A);
    zframe_k<<<nblk(64 * 32 * 124), 256, 0, stream>>>(A, 32);
    // e4: A -> B padded [64,32,32,32]
    conv3_k<32, 32, 8, 1024, 32, 1, 1, false>
        <<<dim3(2, 4, B), 256, 0, stream>>>(A, ew4t, eb4, Bb);
    // e5: B -> A (lat) padded [64,64,32,32]
    conv1_k<32, 64, 8><<<dim3(8, 1, B), 256, 0, stream>>>(Bb, ew5t, eb5, A);
    zframe_k<<<nblk(64 * 64 * 124), 256, 0, stream>>>(Bb, 64);   // z frame

    // ---- VQ: lat=A -> keys -> z=B ----
    vq_argmin_k<<<dim3(nblk(N), 4), 256, 0, stream>>>(A, cb, hcbn, keys, B);
    vq_finalize_k<<<nblk(N), 256, 0, stream>>>(A, cb, keys, Bb, loss, B);

    // ---- decoder ----
    // d1: z=B -> A [64,32,30,(34)] left-pad1, sides zeroed by tx15
    conv3_k<64, 32, 8, 30 * 34, 34, 1, 0, true>
        <<<dim3(2, 4, B), 256, 0, stream>>>(Bb, dw1t, db1, A);
    // d2: A -> B [64,16,63,(66)] left-pad1
    convt2_k<32, 16, 16, 30, 34, 63, 63, 63 * 66, 66, 1, 16, 1, 2, false>
        <<<dim3(8, 1, B), 256, 0, stream>>>(A, dw2t, db2, Bb);
    zsides_k<<<nblk(64 * 16 * 63 * 3 + 64 * 8 * 129 * 3), 256, 0, stream>>>(Bb, A);
    // d3: B -> A [64,8,129,(132)] left-pad1
    convt2_k<16, 8, 8, 63, 66, 129, 129, 129 * 132, 132, 1, 32, 2, 9, false>
        <<<dim3(72, 1, B), 256, 0, stream>>>(Bb, dw3t, db3, A);
    // d4: A -> out [64,1,260,260] + tanh
    convt2_k<8, 1, 1, 129, 132, 260, 260, 67600, 260, 0, 32, 3, 17, true>
        <<<dim3(204, 1, B), 256, 0, stream>>>(A, dw4t, db4, out);

    loss_final_k<<<1, 64, 0, stream>>>(loss, out + (out_size - 1),
                                       1.0f / ((float)N * 64.f));
}

// Round 7
// 499.161 us; speedup vs baseline: 2.6221x; 1.0124x over previous
//
#include <hip/hip_runtime.h>
#include <hip/hip_bf16.h>
#include <math.h>

#define LRELU 0.01f

// ======================= fused prep: weights + cbnorm + zero keys/loss ======
__device__ __forceinline__ void wfwd(const float* s, float* d, int CIN, int COUT,
                                     int KK, int i) {
    int co = i / (CIN * KK); int r = i - co * CIN * KK;
    int ci = r / KK; int t = r - ci * KK;
    d[(ci * KK + t) * COUT + co] = s[i];
}
__device__ __forceinline__ void wtr(const float* s, float* d, int CIN, int COUT,
                                    int KK, int i) {
    int ci = i / (COUT * KK); int r = i - ci * COUT * KK;
    int co = r / KK; int t = r - co * KK;
    d[(t * CIN + ci) * COUT + co] = s[i];
}
__global__ __launch_bounds__(256)
void prep_k(const float* e1, const float* e2, const float* e3, const float* e4,
            const float* e5, const float* d1, const float* d2, const float* d3,
            const float* d4, float* w, const float* cbp, float* hcbn,
            unsigned long long* keys, float* loss, int N) {
    int i = blockIdx.x * 256 + threadIdx.x;
    if      (i < 128)   wfwd(e1, w + 0,     1,  8, 16, i);
    else if (i < 2176)  wfwd(e2, w + 128,   8, 16, 16, i - 128);
    else if (i < 10368) wfwd(e3, w + 2176, 16, 32, 16, i - 2176);
    else if (i < 19584) wfwd(e4, w + 10368, 32, 32, 9, i - 10368);
    else if (i < 21632) wfwd(e5, w + 19584, 32, 64, 1, i - 19584);
    else if (i < 40064) wfwd(d1, w + 21632, 64, 32, 9, i - 21632);
    else if (i < 48256) wtr (d2, w + 40064, 32, 16, 16, i - 40064);
    else if (i < 50304) wtr (d3, w + 48256, 16,  8, 16, i - 48256);
    else if (i < 50432) wtr (d4, w + 50304,  8,  1, 16, i - 50304);   // FIXED index
    else if (i < 50944) {
        int k = i - 50432;
        const float* c = cbp + k * 64;
        float s = 0.f;
#pragma unroll
        for (int d = 0; d < 64; d++) s = fmaf(c[d], c[d], s);
        hcbn[k] = 0.5f * s;
    } else if (i < 50944 + N) {
        keys[i - 50944] = 0xFFFFFFFFFFFFFFFFull;
    } else if (i == 50944 + N) {
        loss[0] = 0.f;
    }
}

// ======================= combined frame zeroing (after e3) ==================
// zero frame (rows 0,31 + cols 0,31) of A e3out [64,32,32,32] and Bb z [64,64,32,32]
__global__ __launch_bounds__(256)
void zframes_k(float* a, float* zb) {
    int i = blockIdx.x * 256 + threadIdx.x;
    const int NA = 64 * 32 * 124;
    const int NZ = 64 * 64 * 124;
    float* p; int j;
    if (i < NA)           { p = a;  j = i; }
    else if (i < NA + NZ) { p = zb; j = i - NA; }
    else return;
    int pl = j / 124, s = j - pl * 124;
    int r, c;
    if (s < 32)      { r = 0;  c = s; }
    else if (s < 64) { r = 31; c = s - 32; }
    else { int u = s - 64; r = 1 + (u >> 1); c = (u & 1) * 31; }
    p[(size_t)pl * 1024 + r * 32 + c] = 0.f;
}
// zero side cols of d2out [64,16,63,66]{0,64,65} and d3out [64,8,129,132]{0,130,131}
__global__ __launch_bounds__(256)
void zsides_k(float* d2o, float* d3o) {
    int i = blockIdx.x * 256 + threadIdx.x;
    const int N2 = 64 * 16 * 63 * 3;
    const int N3 = 64 * 8 * 129 * 3;
    if (i < N2) {
        int pl = i / 189, u = i - pl * 189;
        int r = u / 3, c3 = u - r * 3;
        int col = (c3 == 0) ? 0 : 63 + c3;
        d2o[((size_t)pl * 63 + r) * 66 + col] = 0.f;
    } else if (i < N2 + N3) {
        int j = i - N2;
        int pl = j / 387, u = j - pl * 387;
        int r = u / 3, c3 = u - r * 3;
        int col = (c3 == 0) ? 0 : 129 + c3;
        d3o[((size_t)pl * 129 + r) * 132 + col] = 0.f;
    }
}

// ======================= k4 s2 forward conv, 2px/thread =======================
template<int CIN, int COUT, int CO_BLK, int HIN, int ISTR, int HOUT, int WOUT,
         int OPLANE, int OSTR, int OPAD, int CB, int RB>
__global__ __launch_bounds__(256)
void convs2_k(const float* __restrict__ in, const float* __restrict__ wt,
              const float* __restrict__ bias, float* __restrict__ out) {
    const int bx = blockIdx.x;
    const int cbi = bx / RB, rb = bx - cbi * RB;
    const int tx = threadIdx.x & 15, ty = threadIdx.x >> 4;
    const int cog = blockIdx.y, b = blockIdx.z;
    const int ow0 = (cbi * 16 + tx) * 2;
    const int oh  = rb * 16 + ty;
    if (oh >= HOUT || ow0 >= WOUT) return;
    const bool p1v = (ow0 + 1) < WOUT;

    float acc[CO_BLK][2];
#pragma unroll
    for (int c = 0; c < CO_BLK; c++) {
        float bv = bias[cog * CO_BLK + c];
        acc[c][0] = bv; acc[c][1] = bv;
    }
    const float* inb = in + ((size_t)(b * CIN) * HIN + oh * 2) * ISTR + ow0 * 2;
    const float* wtg = wt + cog * CO_BLK;
#pragma unroll 2
    for (int ci = 0; ci < CIN; ci++) {
        const float* r = inb + (size_t)ci * HIN * ISTR;
        float4 a4[4]; float2 b2[4];
#pragma unroll
        for (int kh = 0; kh < 4; kh++) {
            a4[kh] = *(const float4*)(r + kh * ISTR);
            b2[kh] = p1v ? *(const float2*)(r + kh * ISTR + 4) : make_float2(0.f, 0.f);
        }
        const float* wr = wtg + (size_t)ci * 16 * COUT;
#pragma unroll
        for (int kh = 0; kh < 4; kh++) {
            float x0[4] = {a4[kh].x, a4[kh].y, a4[kh].z, a4[kh].w};
            float x1[4] = {a4[kh].z, a4[kh].w, b2[kh].x, b2[kh].y};
#pragma unroll
            for (int kw = 0; kw < 4; kw++) {
                const float* wv = wr + (kh * 4 + kw) * COUT;
#pragma unroll
                for (int c = 0; c < CO_BLK; c++) {
                    float wgt = wv[c];
                    acc[c][0] = fmaf(x0[kw], wgt, acc[c][0]);
                    acc[c][1] = fmaf(x1[kw], wgt, acc[c][1]);
                }
            }
        }
    }
    float* ob = out + (size_t)(b * COUT + cog * CO_BLK) * OPLANE
                    + (oh + OPAD) * OSTR + ow0 + OPAD;
#pragma unroll
    for (int c = 0; c < CO_BLK; c++) {
        float v0 = acc[c][0]; v0 = (v0 >= 0.f) ? v0 : LRELU * v0;
        ob[(size_t)c * OPLANE] = v0;
        if (p1v) {
            float v1 = acc[c][1]; v1 = (v1 >= 0.f) ? v1 : LRELU * v1;
            ob[(size_t)c * OPLANE + 1] = v1;
        }
    }
}

// ======================= k3 s1 p1 conv on padded [B,C,32,32] input ==========
template<int CIN, int COUT, int CO_BLK, int OPLANE, int OSTR, int OPADH, int OPADV,
         bool ZSIDE>
__global__ __launch_bounds__(256)
void conv3_k(const float* __restrict__ in, const float* __restrict__ wt,
             const float* __restrict__ bias, float* __restrict__ out) {
    const int rb = blockIdx.x;
    const int tx = threadIdx.x & 15, ty = threadIdx.x >> 4;
    const int cog = blockIdx.y, b = blockIdx.z;
    const int r = rb * 16 + ty;
    if (r >= 30) return;
    const int ow0 = tx * 2;
    if (tx == 15) {
        if (ZSIDE) {
#pragma unroll
            for (int c = 0; c < CO_BLK; c++) {
                float* base = out + (size_t)(b * COUT + cog * CO_BLK + c) * OPLANE
                                  + (r + OPADV) * OSTR;
                base[0] = 0.f; base[31] = 0.f; base[32] = 0.f;
            }
        }
        return;
    }
    float acc[CO_BLK][2];
#pragma unroll
    for (int c = 0; c < CO_BLK; c++) {
        float bv = bias[cog * CO_BLK + c];
        acc[c][0] = bv; acc[c][1] = bv;
    }
    const float* inb = in + ((size_t)(b * CIN) * 32 + r) * 32 + ow0;
    const float* wtg = wt + cog * CO_BLK;
#pragma unroll 2
    for (int ci = 0; ci < CIN; ci++) {
        const float* rr = inb + (size_t)ci * 1024;
        float2 A[3], Bv[3];
#pragma unroll
        for (int kh = 0; kh < 3; kh++) {
            A[kh]  = *(const float2*)(rr + kh * 32);
            Bv[kh] = *(const float2*)(rr + kh * 32 + 2);
        }
        const float* wr = wtg + (size_t)ci * 9 * COUT;
#pragma unroll
        for (int kh = 0; kh < 3; kh++) {
            float x0[3] = {A[kh].x, A[kh].y, Bv[kh].x};
            float x1[3] = {A[kh].y, Bv[kh].x, Bv[kh].y};
#pragma unroll
            for (int kw = 0; kw < 3; kw++) {
                const float* wv = wr + (kh * 3 + kw) * COUT;
#pragma unroll
                for (int c = 0; c < CO_BLK; c++) {
                    float wgt = wv[c];
                    acc[c][0] = fmaf(x0[kw], wgt, acc[c][0]);
                    acc[c][1] = fmaf(x1[kw], wgt, acc[c][1]);
                }
            }
        }
    }
    float* ob = out + (size_t)(b * COUT + cog * CO_BLK) * OPLANE
                    + (r + OPADV) * OSTR + ow0 + OPADH;
#pragma unroll
    for (int c = 0; c < CO_BLK; c++) {
        float v0 = acc[c][0]; v0 = (v0 >= 0.f) ? v0 : LRELU * v0;
        float v1 = acc[c][1]; v1 = (v1 >= 0.f) ? v1 : LRELU * v1;
        ob[(size_t)c * OPLANE] = v0;
        ob[(size_t)c * OPLANE + 1] = v1;
    }
}

// ======================= 1x1 conv on padded planes, 4px/thread ==============
template<int CIN, int COUT, int CO_BLK>
__global__ __launch_bounds__(256)
void conv1_k(const float* __restrict__ in, const float* __restrict__ wt,
             const float* __restrict__ bias, float* __restrict__ out) {
    const int px4 = threadIdx.x * 4;
    const int cog = blockIdx.x, b = blockIdx.z;
    float acc[CO_BLK][4];
#pragma unroll
    for (int c = 0; c < CO_BLK; c++) {
        float bv = bias[cog * CO_BLK + c];
        acc[c][0] = bv; acc[c][1] = bv; acc[c][2] = bv; acc[c][3] = bv;
    }
#pragma unroll 4
    for (int ci = 0; ci < CIN; ci++) {
        float4 x = *(const float4*)(in + (size_t)(b * CIN + ci) * 1024 + px4);
        const float* wr = wt + ci * COUT + cog * CO_BLK;
#pragma unroll
        for (int c = 0; c < CO_BLK; c++) {
            float wgt = wr[c];
            acc[c][0] = fmaf(x.x, wgt, acc[c][0]);
            acc[c][1] = fmaf(x.y, wgt, acc[c][1]);
            acc[c][2] = fmaf(x.z, wgt, acc[c][2]);
            acc[c][3] = fmaf(x.w, wgt, acc[c][3]);
        }
    }
#pragma unroll
    for (int c = 0; c < CO_BLK; c++) {
        float4 v;
        v.x = (acc[c][0] >= 0.f) ? acc[c][0] : LRELU * acc[c][0];
        v.y = (acc[c][1] >= 0.f) ? acc[c][1] : LRELU * acc[c][1];
        v.z = (acc[c][2] >= 0.f) ? acc[c][2] : LRELU * acc[c][2];
        v.w = (acc[c][3] >= 0.f) ? acc[c][3] : LRELU * acc[c][3];
        *(float4*)(out + (size_t)(b * COUT + cog * CO_BLK + c) * 1024 + px4) = v;
    }
}

// ======================= convT k4 s2, parity classes, 2px/thread ============
template<int CIN, int COUT, int CO_BLK, int HIN, int ISTR, int HOUT, int WOUT,
         int OPLANE, int OSTR, int OPADH, int TX, int CB, int RB, bool DO_TANH>
__global__ __launch_bounds__(256)
void convt2_k(const float* __restrict__ in, const float* __restrict__ wt,
              const float* __restrict__ bias, float* __restrict__ out) {
    const int x = blockIdx.x;
    const int cls = x / (CB * RB);
    const int rem = x - cls * (CB * RB);
    const int cb = rem / RB, rb = rem - cb * RB;
    const int py = cls & 1, px = cls >> 1;
    const int H2 = (HOUT - py + 1) >> 1;
    const int W2 = (WOUT - px + 1) >> 1;
    const int TY = 256 / TX;
    const int tx = threadIdx.x % TX, ty = threadIdx.x / TX;
    const int o0 = (cb * TX + tx) * 2;
    const int oh2 = rb * TY + ty;
    if (oh2 >= H2 || o0 >= W2) return;
    const bool p1v = (o0 + 1) < W2;
    const int cog = blockIdx.y, b = blockIdx.z;

    float acc[CO_BLK][2];
#pragma unroll
    for (int c = 0; c < CO_BLK; c++) {
        float bv = bias[cog * CO_BLK + c];
        acc[c][0] = bv; acc[c][1] = bv;
    }
#pragma unroll
    for (int a = 0; a < 2; a++) {
        int ih = oh2 - a;
        bool rv = (ih >= 0) && (ih < HIN);
        int kh = py + 2 * a;
        const float* w0b = wt + (size_t)((kh * 4 + px) * CIN) * COUT + cog * CO_BLK;
        const float* w1b = wt + (size_t)((kh * 4 + px + 2) * CIN) * COUT + cog * CO_BLK;
        const float* rowp = in + ((size_t)(b * CIN) * HIN + ih) * ISTR + o0;
#pragma unroll 2
        for (int ci = 0; ci < CIN; ci++) {
            const float* p = rowp + (size_t)ci * HIN * ISTR;
            float2 A  = rv ? *(const float2*)p : make_float2(0.f, 0.f);
            float2 Bv = (rv && p1v) ? *(const float2*)(p + 2) : make_float2(0.f, 0.f);
            const float* w0 = w0b + ci * COUT;
            const float* w1 = w1b + ci * COUT;
#pragma unroll
            for (int c = 0; c < CO_BLK; c++) {
                acc[c][0] = fmaf(A.y, w0[c], acc[c][0]);
                acc[c][0] = fmaf(A.x, w1[c], acc[c][0]);
                acc[c][1] = fmaf(Bv.x, w0[c], acc[c][1]);
                acc[c][1] = fmaf(A.y, w1[c], acc[c][1]);
            }
        }
    }
    const int oh = 2 * oh2 + py, ow = 2 * o0 + px;
    float* ob = out + (size_t)(b * COUT + cog * CO_BLK) * OPLANE + oh * OSTR + ow + OPADH;
#pragma unroll
    for (int c = 0; c < CO_BLK; c++) {
        float v0 = acc[c][0];
        if (!DO_TANH) v0 = (v0 >= 0.f) ? v0 : LRELU * v0; else v0 = tanhf(v0);
        ob[(size_t)c * OPLANE] = v0;
        if (p1v) {
            float v1 = acc[c][1];
            if (!DO_TANH) v1 = (v1 >= 0.f) ? v1 : LRELU * v1; else v1 = tanhf(v1);
            ob[(size_t)c * OPLANE + 2] = v1;
        }
    }
}

// ======================= VQ stage 1: blocked argmin (padded lat) ============
// grid (225, 8): 256 positions/block vs one 64-code eighth. One LDS stage,
// one barrier, no chunk loop. 57600 = 225*256 exactly -> no bounds checks.
__global__ __launch_bounds__(256)
void vq_argmin_k(const float* __restrict__ lat, const float* __restrict__ cb,
                 const float* __restrict__ hcbn,
                 unsigned long long* __restrict__ keys) {
    __shared__ float4 scb4[1024];   // 64 codes x 64 dims = 16KB
    __shared__ float  shn[64];
    const int tid = threadIdx.x;
    const int dq  = tid & 3;
    const int pg  = tid >> 2;
    const int kbase = blockIdx.y * 64;
    const int posbase = blockIdx.x * 256;

    const float4* src = (const float4*)(cb + (size_t)kbase * 64);
#pragma unroll
    for (int i = 0; i < 4; i++) scb4[tid + 256 * i] = src[tid + 256 * i];
    if (tid < 64) shn[tid] = hcbn[kbase + tid];

    float l[4][16];
    int   pidx[4];
#pragma unroll
    for (int j = 0; j < 4; j++) {
        int pos = posbase + pg + 64 * j;
        pidx[j] = pos;
        int b = pos / 900, p = pos - b * 900;
        int oh = p / 30, ow = p - oh * 30;
        int pp = 33 + oh * 32 + ow;
        const float* lb = lat + ((size_t)b * 64 + dq * 16) * 1024 + pp;
#pragma unroll
        for (int i = 0; i < 16; i++) l[j][i] = lb[i * 1024];
    }
    __syncthreads();

    float best[4] = {3.4e38f, 3.4e38f, 3.4e38f, 3.4e38f};
    int   bi[4]   = {0, 0, 0, 0};

#pragma unroll 2
    for (int k0 = 0; k0 < 64; k0++) {
        float4 c0 = scb4[k0 * 16 + dq * 4 + 0];
        float4 c1 = scb4[k0 * 16 + dq * 4 + 1];
        float4 c2 = scb4[k0 * 16 + dq * 4 + 2];
        float4 c3 = scb4[k0 * 16 + dq * 4 + 3];
        float hn = shn[k0];
#pragma unroll
        for (int j = 0; j < 4; j++) {
            float dot = 0.f;
            dot = fmaf(l[j][0],  c0.x, dot); dot = fmaf(l[j][1],  c0.y, dot);
            dot = fmaf(l[j][2],  c0.z, dot); dot = fmaf(l[j][3],  c0.w, dot);
            dot = fmaf(l[j][4],  c1.x, dot); dot = fmaf(l[j][5],  c1.y, dot);
            dot = fmaf(l[j][6],  c1.z, dot); dot = fmaf(l[j][7],  c1.w, dot);
            dot = fmaf(l[j][8],  c2.x, dot); dot = fmaf(l[j][9],  c2.y, dot);
            dot = fmaf(l[j][10], c2.z, dot); dot = fmaf(l[j][11], c2.w, dot);
            dot = fmaf(l[j][12], c3.x, dot); dot = fmaf(l[j][13], c3.y, dot);
            dot = fmaf(l[j][14], c3.z, dot); dot = fmaf(l[j][15], c3.w, dot);
            float full = dot + __shfl_xor(dot, 1);
            full += __shfl_xor(full, 2);
            float score = hn - full;
            if (score < best[j]) { best[j] = score; bi[j] = kbase + k0; }
        }
    }

    if (dq == 0) {
#pragma unroll
        for (int j = 0; j < 4; j++) {
            unsigned u = __float_as_uint(best[j]);
            u = ((int)u < 0) ? ~u : (u | 0x80000000u);
            unsigned long long key = ((unsigned long long)u << 32) | (unsigned)bi[j];
            atomicMin(&keys[pidx[j]], key);
        }
    }
}

// ======================= VQ stage 2: gather, write z (padded), loss =========
__global__ __launch_bounds__(256)
void vq_finalize_k(const float* __restrict__ lat, const float* __restrict__ cb,
                   const unsigned long long* __restrict__ keys,
                   float* __restrict__ z, float* __restrict__ loss_acc, int B) {
    int gid = blockIdx.x * 256 + threadIdx.x;
    const int N = B * 900;
    float myloss = 0.f;
    if (gid < N) {
        int b = gid / 900, p = gid - b * 900;
        int oh = p / 30, ow = p - oh * 30;
        int pp = 33 + oh * 32 + ow;
        int idx = (int)(unsigned)(keys[gid] & 0xFFFFFFFFull);
        const float4* crow = (const float4*)(cb + (size_t)idx * 64);
        const float* lrow = lat + (size_t)b * 64 * 1024 + pp;
        float*       zrow = z   + (size_t)b * 64 * 1024 + pp;
#pragma unroll
        for (int i = 0; i < 16; i++) {
            float4 cv = crow[i];
            float lv0 = lrow[(4 * i + 0) * 1024];
            float lv1 = lrow[(4 * i + 1) * 1024];
            float lv2 = lrow[(4 * i + 2) * 1024];
            float lv3 = lrow[(4 * i + 3) * 1024];
            zrow[(4 * i + 0) * 1024] = cv.x;
            zrow[(4 * i + 1) * 1024] = cv.y;
            zrow[(4 * i + 2) * 1024] = cv.z;
            zrow[(4 * i + 3) * 1024] = cv.w;
            float d0 = cv.x - lv0, d1 = cv.y - lv1, d2 = cv.z - lv2, d3 = cv.w - lv3;
            myloss = fmaf(d0, d0, myloss);
            myloss = fmaf(d1, d1, myloss);
            myloss = fmaf(d2, d2, myloss);
            myloss = fmaf(d3, d3, myloss);
        }
    }
    __shared__ float red[256];
    red[threadIdx.x] = myloss;
    __syncthreads();
    for (int s = 128; s > 0; s >>= 1) {
        if ((int)threadIdx.x < s) red[threadIdx.x] += red[threadIdx.x + s];
        __syncthreads();
    }
    if (threadIdx.x == 0) atomicAdd(loss_acc, red[0]);
}

__global__ void loss_final_k(const float* __restrict__ loss_acc,
                             float* __restrict__ out_last, float inv_n) {
    if (blockIdx.x == 0 && threadIdx.x == 0)
        out_last[0] = 1.25f * loss_acc[0] * inv_n;
}

static inline int nblk(long long total) { return (int)((total + 255) / 256); }

extern "C" void kernel_launch(void* const* d_in, const int* in_sizes, int n_in,
                              void* d_out, int out_size, void* d_ws, size_t ws_size,
                              hipStream_t stream) {
    const float* x   = (const float*)d_in[0];
    const float* ew1 = (const float*)d_in[1];  const float* eb1 = (const float*)d_in[2];
    const float* ew2 = (const float*)d_in[3];  const float* eb2 = (const float*)d_in[4];
    const float* ew3 = (const float*)d_in[5];  const float* eb3 = (const float*)d_in[6];
    const float* ew4 = (const float*)d_in[7];  const float* eb4 = (const float*)d_in[8];
    const float* ew5 = (const float*)d_in[9];  const float* eb5 = (const float*)d_in[10];
    const float* dw1 = (const float*)d_in[11]; const float* db1 = (const float*)d_in[12];
    const float* dw2 = (const float*)d_in[13]; const float* db2 = (const float*)d_in[14];
    const float* dw3 = (const float*)d_in[15]; const float* db3 = (const float*)d_in[16];
    const float* dw4 = (const float*)d_in[17]; const float* db4 = (const float*)d_in[18];
    const float* cb  = (const float*)d_in[19];
    float* out = (float*)d_out;

    const int B = in_sizes[0] / (256 * 256);   // 64
    const int N = B * 900;                     // 57600

    char* ws = (char*)d_ws;
    float* A = (float*)(ws);
    float* Bb = (float*)(ws + 34873344);
    unsigned long long* keys = (unsigned long long*)(ws + 51904512);
    float* hcbn = (float*)(ws + 52365312);
    float* loss = (float*)(ws + 52367360);
    float* wtb  = (float*)(ws + 52367616);
    float* ew1t = wtb;          float* ew2t = wtb + 128;
    float* ew3t = wtb + 2176;   float* ew4t = wtb + 10368;
    float* ew5t = wtb + 19584;  float* dw1t = wtb + 21632;
    float* dw2t = wtb + 40064;  float* dw3t = wtb + 48256;
    float* dw4t = wtb + 50304;

    prep_k<<<nblk(50945 + N), 256, 0, stream>>>(ew1, ew2, ew3, ew4, ew5,
                                                dw1, dw2, dw3, dw4, wtb,
                                                cb, hcbn, keys, loss, N);

    // ---- encoder ----
    // e1: x[64,1,256,256] -> A [64,8,127,(128)]
    convs2_k<1, 8, 8, 256, 256, 127, 127, 127 * 128, 128, 0, 4, 8>
        <<<dim3(32, 1, B), 256, 0, stream>>>(x, ew1t, eb1, A);
    // e2: A -> B [64,16,62,(64)]
    convs2_k<8, 16, 8, 127, 128, 62, 62, 62 * 64, 64, 0, 2, 4>
        <<<dim3(8, 2, B), 256, 0, stream>>>(A, ew2t, eb2, Bb);
    // e3: B -> A padded [64,32,32,32]
    convs2_k<16, 32, 4, 62, 64, 30, 30, 1024, 32, 1, 1, 2>
        <<<dim3(2, 8, B), 256, 0, stream>>>(Bb, ew3t, eb3, A);
    // frames of A(e3out) and Bb(z) — both legal after e3
    zframes_k<<<nblk(64 * 32 * 124 + 64 * 64 * 124), 256, 0, stream>>>(A, Bb);
    // e4: A -> B padded [64,32,32,32]
    conv3_k<32, 32, 4, 1024, 32, 1, 1, false>
        <<<dim3(2, 8, B), 256, 0, stream>>>(A, ew4t, eb4, Bb);
    // e5: B -> A (lat) padded [64,64,32,32]
    conv1_k<32, 64, 4><<<dim3(16, 1, B), 256, 0, stream>>>(Bb, ew5t, eb5, A);

    // ---- VQ: lat=A -> keys -> z=B ----
    vq_argmin_k<<<dim3(225, 8), 256, 0, stream>>>(A, cb, hcbn, keys);
    vq_finalize_k<<<nblk(N), 256, 0, stream>>>(A, cb, keys, Bb, loss, B);

    // ---- decoder ----
    // d1: z=B -> A [64,32,30,(34)] left-pad1, sides zeroed by tx15
    conv3_k<64, 32, 4, 30 * 34, 34, 1, 0, true>
        <<<dim3(2, 8, B), 256, 0, stream>>>(Bb, dw1t, db1, A);
    // d2: A -> B [64,16,63,(66)] left-pad1
    convt2_k<32, 16, 8, 30, 34, 63, 63, 63 * 66, 66, 1, 16, 1, 2, false>
        <<<dim3(8, 2, B), 256, 0, stream>>>(A, dw2t, db2, Bb);
    zsides_k<<<nblk(64 * 16 * 63 * 3 + 64 * 8 * 129 * 3), 256, 0, stream>>>(Bb, A);
    // d3: B -> A [64,8,129,(132)] left-pad1
    convt2_k<16, 8, 8, 63, 66, 129, 129, 129 * 132, 132, 1, 32, 2, 9, false>
        <<<dim3(72, 1, B), 256, 0, stream>>>(Bb, dw3t, db3, A);
    // d4: A -> out [64,1,260,260] + tanh
    convt2_k<8, 1, 1, 129, 132, 260, 260, 67600, 260, 0, 32, 3, 17, true>
        <<<dim3(204, 1, B), 256, 0, stream>>>(A, dw4t, db4, out);

    loss_final_k<<<1, 64, 0, stream>>>(loss, out + (out_size - 1),
                                       1.0f / ((float)N * 64.f));
}